// Round 10
// baseline (3389.841 us; speedup 1.0000x reference)
//
#include <hip/hip_runtime.h>
#include <cstdint>

typedef __attribute__((ext_vector_type(8))) short short8;
typedef __attribute__((ext_vector_type(4))) short s4v;
typedef __attribute__((ext_vector_type(4))) float floatx4;

#define DEV __device__ __forceinline__

DEV short f2bf(float f) {
  unsigned u = __builtin_bit_cast(unsigned, f);
  u += 0x7fffu + ((u >> 16) & 1u);
  return (short)(u >> 16);
}
DEV short f2bf_ru(float f) {
  unsigned u = __builtin_bit_cast(unsigned, f);
  return (short)((u + 0x8000u) >> 16);
}
DEV float bf2f(short s) {
  unsigned u = ((unsigned)(unsigned short)s) << 16;
  return __builtin_bit_cast(float, u);
}
DEV float gelu_exact(float x) {
  return 0.5f * x * (1.0f + erff(x * 0.70710678118654752f));
}
DEV float gelu_fast(float x) {
  const float t2 = 1.5957691216057308f * (x + 0.044715f * x * x * x);
  return x / (1.0f + __expf(-t2));
}
DEV void gload16(const void* g, void* l) {
  __builtin_amdgcn_global_load_lds((const __attribute__((address_space(1))) void*)g,
                                   (__attribute__((address_space(3))) void*)l,
                                   16, 0, 0);
}

// ---------------------------------------------------------------------------
// 128x128-tile bf16 MFMA GEMM, swapped-operand epilogue.  BK=64 main ticks;
// each 64-slice stored as TWO 32-wide sub-slices in the proven XOR layout.
// MODE 0: C = v + bias ; MODE 1: gelu ; MODE 2: + pe ; MODE 3: head-major store
// ---------------------------------------------------------------------------
template<int MODE>
__global__ __launch_bounds__(256)
void gemm_kernel(const short* __restrict__ A, const short* __restrict__ Bw,
                 const float* __restrict__ bias, short* __restrict__ C,
                 const float* __restrict__ pe,
                 int K, int lda, int ldb, int ldc, int Nstore, int NT, long hstride)
{
  __shared__ __align__(16) short lds[128 * 136];
  short* Ct = lds;

  const int tid  = threadIdx.x;
  const int wave = tid >> 6, lane = tid & 63;
  const int quad = lane >> 4, r16 = lane & 15;
  const int per = gridDim.x >> 3;
  const int gti = (blockIdx.x & 7) * per + (blockIdx.x >> 3);
  const int mt = gti / NT, nt = gti - mt * NT;
  const int wm = (wave >> 1) * 64, wn = (wave & 1) * 64;

  const long Abase = (long)mt * 128 * lda;
  const long Bbase = (long)nt * 128 * ldb;

  floatx4 acc[4][4] = {};

  int k0 = 0;
  for (; k0 + 64 <= K; k0 += 64) {
    __syncthreads();
#pragma unroll
    for (int j = 0; j < 8; ++j) {
      const int c2 = tid + j * 256;      // [op(1)|half(1)|sub(9)]
      const int op = c2 >> 10;
      const int cb = c2 & 1023;
      const int half = cb >> 9;
      const int sub = cb & 511;
      const int row = sub >> 2, cc = (sub & 3) ^ ((row >> 1) & 3);
      const short* src = op ? (Bw + Bbase + (long)row * ldb + k0 + half * 32 + cc * 8)
                            : (A  + Abase + (long)row * lda + k0 + half * 32 + cc * 8);
      gload16(src, &lds[(size_t)(op * 8192 + half * 4096 + (sub & ~63) * 8)]);
    }
    __syncthreads();

#pragma unroll
    for (int s = 0; s < 2; ++s) {
      short8 af[4], bfr[4];
#pragma unroll
      for (int i = 0; i < 4; ++i) {
        const int R = wm + i * 16 + r16;
        af[i] = *(const short8*)&lds[s * 4096 + R * 32 + (quad ^ ((R >> 1) & 3)) * 8];
      }
#pragma unroll
      for (int j = 0; j < 4; ++j) {
        const int R = wn + j * 16 + r16;
        bfr[j] = *(const short8*)&lds[8192 + s * 4096 + R * 32 + (quad ^ ((R >> 1) & 3)) * 8];
      }
#pragma unroll
      for (int i = 0; i < 4; ++i)
#pragma unroll
        for (int j = 0; j < 4; ++j)
          acc[i][j] = __builtin_amdgcn_mfma_f32_16x16x32_bf16(bfr[j], af[i], acc[i][j], 0, 0, 0);
    }
  }

  if (k0 < K) {  // 32-wide tail
    short* As = lds;
    short* Bs = lds + 128 * 32;
    const int row0 = tid >> 2,         cc0 = (tid & 3) ^ ((row0 >> 1) & 3);
    const int row1 = (256 + tid) >> 2, cc1 = ((256 + tid) & 3) ^ ((row1 >> 1) & 3);
    __syncthreads();
    gload16(A  + Abase + (long)row0 * lda + k0 + cc0 * 8, &As[(0 * 256 + wave * 64) * 8]);
    gload16(A  + Abase + (long)row1 * lda + k0 + cc1 * 8, &As[(1 * 256 + wave * 64) * 8]);
    gload16(Bw + Bbase + (long)row0 * ldb + k0 + cc0 * 8, &Bs[(0 * 256 + wave * 64) * 8]);
    gload16(Bw + Bbase + (long)row1 * ldb + k0 + cc1 * 8, &Bs[(1 * 256 + wave * 64) * 8]);
    __syncthreads();

    short8 af[4], bfr[4];
#pragma unroll
    for (int i = 0; i < 4; ++i) {
      const int R = wm + i * 16 + r16;
      af[i] = *(const short8*)&As[R * 32 + (quad ^ ((R >> 1) & 3)) * 8];
    }
#pragma unroll
    for (int j = 0; j < 4; ++j) {
      const int R = wn + j * 16 + r16;
      bfr[j] = *(const short8*)&Bs[R * 32 + (quad ^ ((R >> 1) & 3)) * 8];
    }
#pragma unroll
    for (int i = 0; i < 4; ++i)
#pragma unroll
      for (int j = 0; j < 4; ++j)
        acc[i][j] = __builtin_amdgcn_mfma_f32_16x16x32_bf16(bfr[j], af[i], acc[i][j], 0, 0, 0);
  }

  const int mb0 = mt * 128, tb = nt * 128;

  __syncthreads();
#pragma unroll
  for (int j = 0; j < 4; ++j) {
    const int n0 = wn + j * 16 + quad * 4;
    const floatx4 b4 = *(const floatx4*)&bias[tb + n0];
#pragma unroll
    for (int i = 0; i < 4; ++i) {
      const int m = wm + i * 16 + r16;
      floatx4 v = acc[i][j] + b4;
      if (MODE == 1) {
#pragma unroll
        for (int rg = 0; rg < 4; ++rg) v[rg] = gelu_fast(v[rg]);
      }
      if (MODE == 2) {
        const floatx4 p4 = *(const floatx4*)&pe[((mb0 + m) & 127) * 384 + tb + n0];
        v = v + p4;
      }
      s4v o4;
#pragma unroll
      for (int rg = 0; rg < 4; ++rg) o4[rg] = f2bf_ru(v[rg]);
      *(s4v*)&Ct[m * 136 + n0] = o4;
    }
  }
  __syncthreads();

#pragma unroll
  for (int rr = 0; rr < 8; ++rr) {
    const int chunk = rr * 256 + tid;
    const int row = chunk >> 4, ch = chunk & 15;
    const int gcol = tb + ch * 8;
    if (MODE == 3) {
      const int g = gcol / 48, d0 = gcol - g * 48;
      *(short8*)(C + (long)g * hstride + (long)(mb0 + row) * 48 + d0) =
          *(const short8*)&Ct[row * 136 + ch * 8];
    } else if (gcol < Nstore) {
      *(short8*)(C + (long)(mb0 + row) * ldc + gcol) = *(const short8*)&Ct[row * 136 + ch * 8];
    }
  }
}

// ---------------------------------------------------------------------------
// Fused GEMM + residual + LayerNorm, N=288 exact.  M-tile 128, 512 threads.
// Wave-tile 32x144 (4m x 2n wave grid).  Used for the Wo projection.
// ---------------------------------------------------------------------------
template<bool AHEAD>
__global__ __launch_bounds__(512, 4)
void gemm_ln_kernel(const short* __restrict__ A, const short* __restrict__ Bw,
                    const float* __restrict__ bias, short* __restrict__ h,
                    const float* __restrict__ lnw, const float* __restrict__ lnb,
                    const float* __restrict__ skip_p, int layer, int use_skip,
                    int K, int lda, int ldb, long ahs)
{
  __shared__ __align__(16) short lds[128 * 296];
  __shared__ float redp[4][2][2][16];
  __shared__ float reds[4][2][2][16];
  short* Hs = lds;

  const int tid  = threadIdx.x;
  const int wave = tid >> 6, lane = tid & 63;
  const int quad = lane >> 4, r16 = lane & 15;
  const int wr = wave >> 1, wc = wave & 1;
  const int mt = blockIdx.x;
  const long mrow0 = (long)mt * 128;

  floatx4 acc[2][9] = {};

  auto stage = [&](short* buf, int k0) {
    for (int c = tid; c < 1664; c += 512) {
      const void* src;
      if (c < 512) {
        const int row = c >> 2, cc = (c & 3) ^ ((row >> 1) & 3);
        if (AHEAD) {
          const int kc = k0 + cc * 8;
          const int g = kc / 48, d = kc - g * 48;
          src = A + (long)g * ahs + (mrow0 + row) * 48 + d;
        } else {
          src = A + (mrow0 + row) * lda + k0 + cc * 8;
        }
      } else {
        const int cb = c - 512;
        const int row = cb >> 2, cc = (cb & 3) ^ ((row >> 1) & 3);
        src = Bw + (long)row * ldb + k0 + cc * 8;
      }
      gload16(src, &buf[(size_t)(c & ~63) * 8]);
    }
  };

  auto compute = [&](const short* buf) {
    const short* As_ = buf;
    const short* Bs_ = buf + 4096;
    const int Ra0 = wr * 32 + r16, Ra1 = Ra0 + 16;
    const short8 af0 = *(const short8*)&As_[Ra0 * 32 + (quad ^ ((Ra0 >> 1) & 3)) * 8];
    const short8 af1 = *(const short8*)&As_[Ra1 * 32 + (quad ^ ((Ra1 >> 1) & 3)) * 8];
#pragma unroll
    for (int t = 0; t < 9; ++t) {
      const int Rb = wc * 144 + t * 16 + r16;
      const short8 b = *(const short8*)&Bs_[Rb * 32 + (quad ^ ((Rb >> 1) & 3)) * 8];
      acc[0][t] = __builtin_amdgcn_mfma_f32_16x16x32_bf16(b, af0, acc[0][t], 0, 0, 0);
      acc[1][t] = __builtin_amdgcn_mfma_f32_16x16x32_bf16(b, af1, acc[1][t], 0, 0, 0);
    }
  };

  short* const B0 = lds;
  short* const B1 = lds + 13312;

  stage(B0, 0);
  __syncthreads();
  int k0 = 0;
  while (true) {
    if (k0 + 32 < K) stage(B1, k0 + 32);
    compute(B0);
    __syncthreads();
    k0 += 32;
    if (k0 >= K) break;
    if (k0 + 32 < K) stage(B0, k0 + 32);
    compute(B1);
    __syncthreads();
    k0 += 32;
    if (k0 >= K) break;
  }

  for (int c = tid; c < 4608; c += 512) {
    const int row = c / 36, ch = c - row * 36;
    *(short8*)&Hs[row * 296 + ch * 8] =
        *(const short8*)(h + (mrow0 + row) * 288 + ch * 8);
  }
  __syncthreads();

  const float skipv = use_skip ? skip_p[layer] : 1.0f;
  const int m0 = wr * 32 + r16, m1 = m0 + 16;

  float ps0 = 0.f, ss0 = 0.f, ps1 = 0.f, ss1 = 0.f;
#pragma unroll
  for (int t = 0; t < 9; ++t) {
    const int n0 = wc * 144 + t * 16 + quad * 4;
    const floatx4 b4 = *(const floatx4*)&bias[n0];
    const s4v h40 = *(const s4v*)&Hs[m0 * 296 + n0];
    const s4v h41 = *(const s4v*)&Hs[m1 * 296 + n0];
#pragma unroll
    for (int rg = 0; rg < 4; ++rg) {
      const float y0 = bf2f(h40[rg]) + skipv * (acc[0][t][rg] + b4[rg]);
      const float y1 = bf2f(h41[rg]) + skipv * (acc[1][t][rg] + b4[rg]);
      acc[0][t][rg] = y0; acc[1][t][rg] = y1;
      ps0 += y0; ss0 += y0 * y0;
      ps1 += y1; ss1 += y1 * y1;
    }
  }
  ps0 += __shfl_xor(ps0, 16); ps0 += __shfl_xor(ps0, 32);
  ss0 += __shfl_xor(ss0, 16); ss0 += __shfl_xor(ss0, 32);
  ps1 += __shfl_xor(ps1, 16); ps1 += __shfl_xor(ps1, 32);
  ss1 += __shfl_xor(ss1, 16); ss1 += __shfl_xor(ss1, 32);
  if (lane < 16) {
    redp[wr][wc][0][r16] = ps0; redp[wr][wc][1][r16] = ps1;
    reds[wr][wc][0][r16] = ss0; reds[wr][wc][1][r16] = ss1;
  }
  __syncthreads();
  const float psum0 = redp[wr][0][0][r16] + redp[wr][1][0][r16];
  const float psum1 = redp[wr][0][1][r16] + redp[wr][1][1][r16];
  const float ssum0 = reds[wr][0][0][r16] + reds[wr][1][0][r16];
  const float ssum1 = reds[wr][0][1][r16] + reds[wr][1][1][r16];
  const float mean0 = psum0 * (1.f / 288.f), mean1 = psum1 * (1.f / 288.f);
  const float rstd0 = rsqrtf(ssum0 * (1.f / 288.f) - mean0 * mean0 + 1e-5f);
  const float rstd1 = rsqrtf(ssum1 * (1.f / 288.f) - mean1 * mean1 + 1e-5f);

#pragma unroll
  for (int t = 0; t < 9; ++t) {
    const int n0 = wc * 144 + t * 16 + quad * 4;
    const floatx4 w4 = *(const floatx4*)&lnw[n0];
    const floatx4 l4 = *(const floatx4*)&lnb[n0];
    s4v o0, o1;
#pragma unroll
    for (int rg = 0; rg < 4; ++rg) {
      o0[rg] = f2bf_ru((acc[0][t][rg] - mean0) * rstd0 * w4[rg] + l4[rg]);
      o1[rg] = f2bf_ru((acc[1][t][rg] - mean1) * rstd1 * w4[rg] + l4[rg]);
    }
    *(s4v*)&Hs[m0 * 296 + n0] = o0;
    *(s4v*)&Hs[m1 * 296 + n0] = o1;
  }
  __syncthreads();

  for (int c = tid; c < 4608; c += 512) {
    const int row = c / 36, ch = c - row * 36;
    *(short8*)(h + (mrow0 + row) * 288 + ch * 8) =
        *(const short8*)&Hs[row * 296 + ch * 8];
  }
}

// ---------------------------------------------------------------------------
// FUSED FFN with counted-vmcnt ticks (T3/T4).  5 ticks/chunk, per tick:
//   stage(Sn)  ->  s_waitcnt vmcnt(N_t)  ->  s_barrier  ->  compute(Sc)
//   ->  s_waitcnt lgkmcnt(0)  ->  s_barrier
// The counted wait leaves THIS tick's loads in flight across the barrier;
// the previous tick's loads have had a full tick to land (wait ~ free).
// Per-thread load counts are UNIFORM per tick (W2 stage padded to 5 by
// benign duplicate writes).  b1 is pre-staged to LDS so compute ticks issue
// no global loads (vmcnt FIFO stays clean).
// Ring 2x18432 shorts + f 16384 shorts + b1s = ~112KB, 1 blk/CU.
// ---------------------------------------------------------------------------
__global__ __launch_bounds__(512, 2)
void ffn_kernel(short* __restrict__ h,
                const short* __restrict__ W1, const float* __restrict__ b1,
                const short* __restrict__ W2, const float* __restrict__ b2,
                const float* __restrict__ lnw, const float* __restrict__ lnb)
{
  __shared__ __align__(16) short lds[53248];   // ring 2x18432 + f 16384
  __shared__ __align__(16) float b1s[1408];
  __shared__ float redp[4][2][2][16];
  __shared__ float reds[4][2][2][16];
  short* const fl = lds + 36864;               // f: [4 ks][128 m][32]

  const int tid  = threadIdx.x;
  const int wave = tid >> 6, lane = tid & 63;
  const int quad = lane >> 4, r16 = lane & 15;
  const int wr = wave >> 1, wp = wave & 1;
  const long mrow0 = (long)blockIdx.x * 128;

  // persist h A-fragments across chunks (chunk-invariant; drained by the
  // first counted vmcnt wait before their first MFMA use)
  short8 ha[2][9];
#pragma unroll
  for (int i = 0; i < 2; ++i) {
    const long rb = (mrow0 + wr * 32 + i * 16 + r16) * 288L;
#pragma unroll
    for (int k9 = 0; k9 < 9; ++k9)
      ha[i][k9] = *(const short8*)(h + rb + k9 * 32 + quad * 8);
  }

  // b1 -> LDS (removes global loads from tick C)
  for (int i = tid; i < 1408; i += 512) b1s[i] = b1[i];

  floatx4 acc2[2][9] = {};

  // stage W1 [c*128..+128) x k[kb..kb+128): 4 uniform loads/thread
  auto stageW1_128 = [&](int c, int kb, short* dst) {
#pragma unroll
    for (int j = 0; j < 4; ++j) {
      const int c2t = tid + j * 512;
      const int s = c2t >> 9, c2 = c2t & 511;
      const int row = c2 >> 2, cc = (c2 & 3) ^ ((row >> 1) & 3);
      gload16(W1 + ((long)(c * 128 + row)) * 288 + kb + s * 32 + cc * 8,
              &dst[(size_t)(s * 4096 + (c2 & ~63) * 8)]);
    }
  };
  // W1 tail (k=256..288): 1 uniform load/thread
  auto stageW1_32 = [&](int c, short* dst) {
    const int row = tid >> 2, cc = (tid & 3) ^ ((row >> 1) & 3);
    gload16(W1 + ((long)(c * 128 + row)) * 288 + 256 + cc * 8,
            &dst[(size_t)(tid & ~63) * 8]);
  };
  // W2 [0..288) x k[kb..kb+64): padded to 5 uniform loads/thread.
  // Threads with c2t>=2304 re-load chunks 0..255 (same src, same dst:
  // identical bytes double-written -> benign).
  auto stageW2_64 = [&](int c, int kb, short* dst) {
#pragma unroll
    for (int j = 0; j < 5; ++j) {
      int c2t = tid + j * 512;
      if (c2t >= 2304) c2t -= 2304;
      const int s = (c2t >= 1152) ? 1 : 0;
      const int c2 = c2t - s * 1152;
      const int row = c2 >> 2, cc = (c2 & 3) ^ ((row >> 1) & 3);
      gload16(W2 + (long)row * 1408 + c * 128 + kb + s * 32 + cc * 8,
              &dst[(size_t)(s * 9216 + (c2 & ~63) * 8)]);
    }
  };

  short* const ring0 = lds;
  short* const ring1 = lds + 18432;

  // initial stage (left in flight across the barrier; drained at tick A's wait)
  stageW1_128(0, 0, ring0);
  asm volatile("s_waitcnt lgkmcnt(0)" ::: "memory");   // b1s writes visible
  asm volatile("s_barrier" ::: "memory");
  __builtin_amdgcn_sched_barrier(0);
  int cur = 0;

  for (int c = 0; c < 11; ++c) {
    floatx4 acc1[2][4] = {};

    // G1 over a staged k128 slice (4 sub-slices), ha indices hb..hb+3
    auto g1_128 = [&](const short* Sc, int hb) {
#pragma unroll
      for (int s = 0; s < 4; ++s) {
        short8 bfr[4];
#pragma unroll
        for (int j = 0; j < 4; ++j) {
          const int R = wp * 64 + j * 16 + r16;
          bfr[j] = *(const short8*)&Sc[s * 4096 + R * 32 + (quad ^ ((R >> 1) & 3)) * 8];
        }
#pragma unroll
        for (int i = 0; i < 2; ++i)
#pragma unroll
          for (int j = 0; j < 4; ++j)
            acc1[i][j] = __builtin_amdgcn_mfma_f32_16x16x32_bf16(bfr[j], ha[i][hb + s], acc1[i][j], 0, 0, 0);
      }
    };

    // ---- tick A: stage W1 k128-255 (4 loads) | compute G1 k0-127 ----
    {
      short* const Sn = cur ? ring0 : ring1;
      const short* Sc = cur ? ring1 : ring0;
      stageW1_128(c, 128, Sn);
      asm volatile("s_waitcnt vmcnt(4)" ::: "memory");
      asm volatile("s_barrier" ::: "memory");
      __builtin_amdgcn_sched_barrier(0);
      g1_128(Sc, 0);
      asm volatile("s_waitcnt lgkmcnt(0)" ::: "memory");
      asm volatile("s_barrier" ::: "memory");
      __builtin_amdgcn_sched_barrier(0);
      cur ^= 1;
    }
    // ---- tick B: stage W1 tail (1 load) | compute G1 k128-255 ----
    {
      short* const Sn = cur ? ring0 : ring1;
      const short* Sc = cur ? ring1 : ring0;
      stageW1_32(c, Sn);
      asm volatile("s_waitcnt vmcnt(1)" ::: "memory");
      asm volatile("s_barrier" ::: "memory");
      __builtin_amdgcn_sched_barrier(0);
      g1_128(Sc, 4);
      asm volatile("s_waitcnt lgkmcnt(0)" ::: "memory");
      asm volatile("s_barrier" ::: "memory");
      __builtin_amdgcn_sched_barrier(0);
      cur ^= 1;
    }
    // ---- tick C: stage W2 k0-63 (5 loads) | tail MFMA + gelu -> f ----
    {
      short* const Sn = cur ? ring0 : ring1;
      const short* Sc = cur ? ring1 : ring0;
      stageW2_64(c, 0, Sn);
      asm volatile("s_waitcnt vmcnt(5)" ::: "memory");
      asm volatile("s_barrier" ::: "memory");
      __builtin_amdgcn_sched_barrier(0);

      short8 bfr[4];
#pragma unroll
      for (int j = 0; j < 4; ++j) {
        const int R = wp * 64 + j * 16 + r16;
        bfr[j] = *(const short8*)&Sc[R * 32 + (quad ^ ((R >> 1) & 3)) * 8];
      }
#pragma unroll
      for (int i = 0; i < 2; ++i)
#pragma unroll
        for (int j = 0; j < 4; ++j)
          acc1[i][j] = __builtin_amdgcn_mfma_f32_16x16x32_bf16(bfr[j], ha[i][8], acc1[i][j], 0, 0, 0);

      // f write in the proven MFMA-staged layout (b1 from LDS)
#pragma unroll
      for (int i = 0; i < 2; ++i) {
        const int m = wr * 32 + i * 16 + r16;
#pragma unroll
        for (int j = 0; j < 4; ++j) {
          const int nb = c * 128 + wp * 64 + j * 16 + quad * 4;
          const floatx4 b4 = *(const floatx4*)&b1s[nb];
          s4v o;
#pragma unroll
          for (int rg = 0; rg < 4; ++rg)
            o[rg] = f2bf_ru(gelu_fast(acc1[i][j][rg] + b4[rg]));
          const int ks = wp * 2 + (j >> 1);
          const int mg = ((j & 1) * 2 + (quad >> 1)) ^ ((m >> 1) & 3);
          *(s4v*)&fl[ks * 4096 + m * 32 + mg * 8 + (quad & 1) * 4] = o;
        }
      }
      asm volatile("s_waitcnt lgkmcnt(0)" ::: "memory");
      asm volatile("s_barrier" ::: "memory");
      __builtin_amdgcn_sched_barrier(0);
      cur ^= 1;
    }
    // ---- ticks D, E: G2 over W2 k64 slices ----
#pragma unroll
    for (int g2t = 0; g2t < 2; ++g2t) {
      short* const Sn = cur ? ring0 : ring1;
      const short* Sc = cur ? ring1 : ring0;
      if (g2t == 0) {
        stageW2_64(c, 64, Sn);
        asm volatile("s_waitcnt vmcnt(5)" ::: "memory");
      } else if (c < 10) {
        stageW1_128(c + 1, 0, Sn);
        asm volatile("s_waitcnt vmcnt(4)" ::: "memory");
      } else {
        asm volatile("s_waitcnt vmcnt(0)" ::: "memory");
      }
      asm volatile("s_barrier" ::: "memory");
      __builtin_amdgcn_sched_barrier(0);

#pragma unroll
      for (int s = 0; s < 2; ++s) {
        const int ks = g2t * 2 + s;
        short8 af2[2];
#pragma unroll
        for (int i = 0; i < 2; ++i) {
          const int R = wr * 32 + i * 16 + r16;
          af2[i] = *(const short8*)&fl[ks * 4096 + R * 32 + (quad ^ ((R >> 1) & 3)) * 8];
        }
        short8 br[9];
#pragma unroll
        for (int t = 0; t < 9; ++t) {
          const int R = wp * 144 + t * 16 + r16;
          br[t] = *(const short8*)&Sc[s * 9216 + R * 32 + (quad ^ ((R >> 1) & 3)) * 8];
        }
#pragma unroll
        for (int i = 0; i < 2; ++i)
#pragma unroll
          for (int t = 0; t < 9; ++t)
            acc2[i][t] = __builtin_amdgcn_mfma_f32_16x16x32_bf16(br[t], af2[i], acc2[i][t], 0, 0, 0);
      }
      asm volatile("s_waitcnt lgkmcnt(0)" ::: "memory");
      asm volatile("s_barrier" ::: "memory");
      __builtin_amdgcn_sched_barrier(0);
      cur ^= 1;
    }
  }

  // ---- residual + LayerNorm epilogue (128 rows); vmcnt is fully drained ----
  for (int c2 = tid; c2 < 4608; c2 += 512) {
    const int row = c2 / 36, ch = c2 - row * 36;
    *(short8*)&lds[row * 296 + ch * 8] =
        *(const short8*)(h + (mrow0 + row) * 288 + ch * 8);
  }
  __syncthreads();

  const int m0 = wr * 32 + r16, m1 = m0 + 16;
  float ps0 = 0.f, ss0 = 0.f, ps1 = 0.f, ss1 = 0.f;
#pragma unroll
  for (int t = 0; t < 9; ++t) {
    const int n0 = wp * 144 + t * 16 + quad * 4;
    const floatx4 b4 = *(const floatx4*)&b2[n0];
    const s4v h40 = *(const s4v*)&lds[m0 * 296 + n0];
    const s4v h41 = *(const s4v*)&lds[m1 * 296 + n0];
#pragma unroll
    for (int rg = 0; rg < 4; ++rg) {
      const float y0 = bf2f(h40[rg]) + acc2[0][t][rg] + b4[rg];
      const float y1 = bf2f(h41[rg]) + acc2[1][t][rg] + b4[rg];
      acc2[0][t][rg] = y0; acc2[1][t][rg] = y1;
      ps0 += y0; ss0 += y0 * y0;
      ps1 += y1; ss1 += y1 * y1;
    }
  }
  ps0 += __shfl_xor(ps0, 16); ps0 += __shfl_xor(ps0, 32);
  ss0 += __shfl_xor(ss0, 16); ss0 += __shfl_xor(ss0, 32);
  ps1 += __shfl_xor(ps1, 16); ps1 += __shfl_xor(ps1, 32);
  ss1 += __shfl_xor(ss1, 16); ss1 += __shfl_xor(ss1, 32);
  if (lane < 16) {
    redp[wr][wp][0][r16] = ps0; redp[wr][wp][1][r16] = ps1;
    reds[wr][wp][0][r16] = ss0; reds[wr][wp][1][r16] = ss1;
  }
  __syncthreads();
  const float psum0 = redp[wr][0][0][r16] + redp[wr][1][0][r16];
  const float psum1 = redp[wr][0][1][r16] + redp[wr][1][1][r16];
  const float ssum0 = reds[wr][0][0][r16] + reds[wr][1][0][r16];
  const float ssum1 = reds[wr][0][1][r16] + reds[wr][1][1][r16];
  const float mean0 = psum0 * (1.f / 288.f), mean1 = psum1 * (1.f / 288.f);
  const float rstd0 = rsqrtf(ssum0 * (1.f / 288.f) - mean0 * mean0 + 1e-5f);
  const float rstd1 = rsqrtf(ssum1 * (1.f / 288.f) - mean1 * mean1 + 1e-5f);

#pragma unroll
  for (int t = 0; t < 9; ++t) {
    const int n0 = wp * 144 + t * 16 + quad * 4;
    const floatx4 w4 = *(const floatx4*)&lnw[n0];
    const floatx4 l4 = *(const floatx4*)&lnb[n0];
    s4v o0, o1;
#pragma unroll
    for (int rg = 0; rg < 4; ++rg) {
      o0[rg] = f2bf_ru((acc2[0][t][rg] - mean0) * rstd0 * w4[rg] + l4[rg]);
      o1[rg] = f2bf_ru((acc2[1][t][rg] - mean1) * rstd1 * w4[rg] + l4[rg]);
    }
    *(s4v*)&lds[m0 * 296 + n0] = o0;
    *(s4v*)&lds[m1 * 296 + n0] = o1;
  }
  __syncthreads();

  for (int c2 = tid; c2 < 4608; c2 += 512) {
    const int row = c2 / 36, ch = c2 - row * 36;
    *(short8*)(h + (mrow0 + row) * 288 + ch * 8) =
        *(const short8*)&lds[row * 296 + ch * 8];
  }
}

// ---------------------------------------------------------------------------
// Attention.  qkv head-major [24][Mc][48]; q pre-scaled by 1/(sqrt(41)*temp)
// at weight conversion.
// ---------------------------------------------------------------------------
__global__ __launch_bounds__(256)
void attn_kernel(short* __restrict__ qkv,
                 const float* __restrict__ qscale, int layer, long Mc)
{
  __shared__ __align__(16) short qk[2 * 128 * 72];   // qs|ks, later Pb[128][136]
  __shared__ __align__(16) short vsT[48 * 136 + 32]; // [d][s], skew ((d>>3)&3)*8
  __shared__ float red[2][2][64];

  short* qs = qk;
  short* ks = qk + 128 * 72;
  short* Pb = qk;

  const int b = blockIdx.x, h = blockIdx.y;
  const int tid = threadIdx.x;
  const long sec = Mc * 48;
  const short* qg = qkv + (long)h * sec + (long)b * 128 * 48;
  const short* kg = qg + 8 * sec;
  const short* vg = qg + 16 * sec;
  short* og = qkv + (long)(16 + h) * sec + (long)b * 128 * 48;

  for (int c = tid; c < 768; c += 256) {
    const int s = c / 6, dc = c - (c / 6) * 6;
    *(short8*)&qs[s * 72 + dc * 8] = *(const short8*)(qg + (long)s * 48 + dc * 8);
    *(short8*)&ks[s * 72 + dc * 8] = *(const short8*)(kg + (long)s * 48 + dc * 8);
  }
  {
    short8 z;
#pragma unroll
    for (int j = 0; j < 8; ++j) z[j] = 0;
    for (int c = tid; c < 384; c += 256) {
      const int s = c / 3, t = c - (c / 3) * 3;
      *(short8*)&qs[s * 72 + 48 + t * 8] = z;
      *(short8*)&ks[s * 72 + 48 + t * 8] = z;
    }
  }
  for (int c = tid; c < 768; c += 256) {
    const int s = c & 127, dc = c >> 7;
    const short8 tv = *(const short8*)(vg + (long)s * 48 + dc * 8);
#pragma unroll
    for (int j = 0; j < 8; ++j) {
      const int row = dc * 8 + j;
      vsT[row * 136 + ((row >> 3) & 3) * 8 + s] = tv[j];
    }
  }
  __syncthreads();

  const int wave = tid >> 6, lane = tid & 63;
  const int quad = lane >> 4, r16 = lane & 15;
  const int wm = (wave >> 1) * 64, wn = (wave & 1) * 64;
  const int rh = wave >> 1, ch = wave & 1;
  const float qsc = qscale[layer * 8 + h];

  floatx4 acc[4][4] = {};
#pragma unroll
  for (int kk = 0; kk < 2; ++kk) {
    const int k0 = kk * 32;
    short8 af[4], bfr[4];
#pragma unroll
    for (int i = 0; i < 4; ++i)
      af[i] = *(const short8*)&qs[(wm + i * 16 + r16) * 72 + k0 + quad * 8];
#pragma unroll
    for (int j = 0; j < 4; ++j)
      bfr[j] = *(const short8*)&ks[(wn + j * 16 + r16) * 72 + k0 + quad * 8];
#pragma unroll
    for (int i = 0; i < 4; ++i)
#pragma unroll
      for (int j = 0; j < 4; ++j)
        acc[i][j] = __builtin_amdgcn_mfma_f32_16x16x32_bf16(bfr[j], af[i], acc[i][j], 0, 0, 0);
  }

  float rmax[4], rsum[4];
#pragma unroll
  for (int i = 0; i < 4; ++i) {
    float m = acc[i][0][0];
#pragma unroll
    for (int j = 0; j < 4; ++j)
#pragma unroll
      for (int rg = 0; rg < 4; ++rg) m = fmaxf(m, acc[i][j][rg]);
    m = fmaxf(m, __shfl_xor(m, 16));
    m = fmaxf(m, __shfl_xor(m, 32));
    rmax[i] = m;
  }
  if (lane < 16)
#pragma unroll
    for (int i = 0; i < 4; ++i) red[rh][ch][i * 16 + r16] = rmax[i];
  __syncthreads();
#pragma unroll
  for (int i = 0; i < 4; ++i)
    rmax[i] = fmaxf(red[rh][0][i * 16 + r16], red[rh][1][i * 16 + r16]);

#pragma unroll
  for (int i = 0; i < 4; ++i) {
    float s = 0.f;
#pragma unroll
    for (int j = 0; j < 4; ++j)
#pragma unroll
      for (int rg = 0; rg < 4; ++rg) {
        const float e = __expf(acc[i][j][rg] - rmax[i]);
        acc[i][j][rg] = e;
        s += e;
      }
    s += __shfl_xor(s, 16);
    s += __shfl_xor(s, 32);
    rsum[i] = s;
  }
  __syncthreads();
  if (lane < 16)
#pragma unroll
    for (int i = 0; i < 4; ++i) red[rh][ch][i * 16 + r16] = rsum[i];
  __syncthreads();
#pragma unroll
  for (int i = 0; i < 4; ++i)
    rmax[i] = qsc / (red[rh][0][i * 16 + r16] + red[rh][1][i * 16 + r16]);

#pragma unroll
  for (int i = 0; i < 4; ++i) {
    const int sq = wm + i * 16 + r16;
#pragma unroll
    for (int j = 0; j < 4; ++j) {
      const int sk0 = wn + j * 16 + quad * 4;
      s4v p4;
#pragma unroll
      for (int rg = 0; rg < 4; ++rg) p4[rg] = f2bf_ru(acc[i][j][rg] * rmax[i]);
      *(s4v*)&Pb[sq * 136 + sk0] = p4;
    }
  }
  __syncthreads();

  const int om = (wave >> 1) * 64, on = (wave & 1) * 32;
  const int jn = (on == 0) ? 2 : 1;
  floatx4 oacc[4][2] = {};
  for (int kk = 0; kk < 4; ++kk) {
    const int k0 = kk * 32;
    short8 af[4], bfr[2];
#pragma unroll
    for (int i = 0; i < 4; ++i)
      af[i] = *(const short8*)&Pb[(om + i * 16 + r16) * 136 + k0 + quad * 8];
    for (int j = 0; j < jn; ++j) {
      const int row = on + j * 16 + r16;
      bfr[j] = *(const short8*)&vsT[row * 136 + ((row >> 3) & 3) * 8 + k0 + quad * 8];
    }
#pragma unroll
    for (int i = 0; i < 4; ++i)
      for (int j = 0; j < jn; ++j)
        oacc[i][j] = __builtin_amdgcn_mfma_f32_16x16x32_bf16(bfr[j], af[i], oacc[i][j], 0, 0, 0);
  }
#pragma unroll
  for (int i = 0; i < 4; ++i)
    for (int j = 0; j < jn; ++j) {
      const int d0 = on + j * 16 + quad * 4;
      const int sq = om + i * 16 + r16;
      s4v o4;
#pragma unroll
      for (int rg = 0; rg < 4; ++rg) o4[rg] = f2bf_ru(oacc[i][j][rg]);
      *(s4v*)(og + (long)sq * 48 + d0) = o4;
    }
}

// ---------------------------------------------------------------------------
// Pool over S + BN + GELU MLP head + uncertainty head.  Block per b.
// ---------------------------------------------------------------------------
__global__ __launch_bounds__(256)
void head_kernel(const short* __restrict__ hb, float* __restrict__ out,
                 const float* bn_w, const float* bn_b, const float* bn_mean, const float* bn_var,
                 const float* h1w, const float* h1b, const float* h2w, const float* h2b,
                 const float* h3w, const float* h3b,
                 const float* u1w, const float* u1b, const float* u2w, const float* u2b)
{
  __shared__ float psum[252][8];
  __shared__ float pooled[288], z[288], z1[144], z2[72], uu[72];
  const int b = blockIdx.x, tid = threadIdx.x;

  if (tid < 252) {
    const int cch = tid % 36, grp = tid / 36;
    float a[8];
#pragma unroll
    for (int j = 0; j < 8; ++j) a[j] = 0.f;
    for (int r = grp; r < 128; r += 7) {
      const short8 hv = *(const short8*)(hb + ((long)b * 128 + r) * 288 + cch * 8);
#pragma unroll
      for (int j = 0; j < 8; ++j) a[j] += bf2f(hv[j]);
    }
#pragma unroll
    for (int j = 0; j < 8; ++j) psum[tid][j] = a[j];
  }
  __syncthreads();
  for (int d = tid; d < 288; d += 256) {
    const int cch = d >> 3, j = d & 7;
    float s = 0.f;
#pragma unroll
    for (int g = 0; g < 7; ++g) s += psum[g * 36 + cch][j];
    pooled[d] = s * (1.f / 128.f);
  }
  __syncthreads();

  for (int d = tid; d < 288; d += 256) {
    const float p = pooled[d];
    z[d] = gelu_exact((p - bn_mean[d]) * rsqrtf(bn_var[d] + 1e-5f) * bn_w[d] + bn_b[d]);
  }
  __syncthreads();

  if (tid < 144) {
    float s = h1b[tid];
    for (int k = 0; k < 288; ++k) s += z[k] * h1w[tid * 288 + k];
    z1[tid] = gelu_exact(s);
  } else if (tid < 216) {
    const int t = tid - 144;
    float s = u1b[t];
    for (int k = 0; k < 288; ++k) s += pooled[k] * u1w[t * 288 + k];
    uu[t] = fmaxf(s, 0.f);
  }
  __syncthreads();

  if (tid < 72) {
    float s = h2b[tid];
    for (int k = 0; k < 144; ++k) s += z1[k] * h2w[tid * 144 + k];
    z2[tid] = gelu_exact(s);
  }
  __syncthreads();

  if (tid == 0) {
    float s = h3b[0];
    for (int k = 0; k < 72; ++k) s += z2[k] * h3w[k];
    out[b] = s;
  }
  if (tid == 64) {
    float s = u2b[0];
    for (int k = 0; k < 72; ++k) s += uu[k] * u2w[k];
    out[1024 + b] = (s > 20.f) ? s : log1pf(__expf(s));
  }
}

// ---------------------------------------------------------------------------
// Conversion / padding kernels
// ---------------------------------------------------------------------------
__global__ void conv_w_kernel(const float* __restrict__ src, short* __restrict__ dst,
                              int N, int K, int Npad, int Kpad, int total)
{
  const int i = blockIdx.x * 256 + threadIdx.x;
  if (i >= total) return;
  const int kk = i % Kpad;
  const int t  = i / Kpad;
  const int n  = t % Npad;
  const int l  = t / Npad;
  const float v = (n < N && kk < K) ? src[((long)l * N + n) * K + kk] : 0.f;
  dst[i] = f2bf(v);
}

__global__ void conv_b_kernel(const float* __restrict__ src, float* __restrict__ dst,
                              int N, int Npad, int total)
{
  const int i = blockIdx.x * 256 + threadIdx.x;
  if (i >= total) return;
  const int n = i % Npad, l = i / Npad;
  dst[i] = (n < N) ? src[l * N + n] : 0.f;
}

// q-section (sec==0) pre-scaled by 1/(sqrt(41)*temp[l])
__global__ void conv_wqkv_kernel(const float* __restrict__ Wq, const float* __restrict__ Wk,
                                 const float* __restrict__ Wv, const float* __restrict__ temp,
                                 short* __restrict__ dst)
{
  const int i = blockIdx.x * 256 + threadIdx.x;
  if (i >= 4 * 1152 * 288) return;
  const int kk = i % 288;
  const int t  = i / 288;
  const int r  = t % 1152;
  const int l  = t / 1152;
  const int g  = r / 48, d = r - (r / 48) * 48;
  const int sec = g >> 3, head = g & 7;
  float v = 0.f;
  if (d < 41) {
    const float* W = (sec == 0) ? Wq : (sec == 1) ? Wk : Wv;
    v = W[((long)l * 328 + head * 41 + d) * 288 + kk];
    if (sec == 0) v *= 1.0f / (6.4031242374328485f * temp[l]);
  }
  dst[i] = f2bf(v);
}

__global__ void conv_bqkv_kernel(const float* __restrict__ bq, const float* __restrict__ bk,
                                 const float* __restrict__ bv, const float* __restrict__ temp,
                                 float* __restrict__ dst)
{
  const int i = blockIdx.x * 256 + threadIdx.x;
  if (i >= 4 * 1152) return;
  const int r = i % 1152, l = i / 1152;
  const int g = r / 48, d = r - (r / 48) * 48;
  const int sec = g >> 3, head = g & 7;
  float v = 0.f;
  if (d < 41) {
    const float* b = (sec == 0) ? bq : (sec == 1) ? bk : bv;
    v = b[l * 328 + head * 41 + d];
    if (sec == 0) v *= 1.0f / (6.4031242374328485f * temp[l]);
  }
  dst[i] = v;
}

__global__ void conv_wo_kernel(const float* __restrict__ Wo, short* __restrict__ dst)
{
  const int i = blockIdx.x * 256 + threadIdx.x;
  if (i >= 4 * 288 * 384) return;
  const int kk = i % 384;
  const int t  = i / 384;
  const int n  = t % 288;
  const int l  = t / 288;
  const int head = kk / 48, d = kk - head * 48;
  float v = 0.f;
  if (d < 41) v = Wo[((long)l * 288 + n) * 328 + head * 41 + d];
  dst[i] = f2bf(v);
}

__global__ void conv_x_kernel(const float* __restrict__ x, short* __restrict__ xb, int total)
{
  const int i = blockIdx.x * 256 + threadIdx.x;
  if (i >= total) return;
  const int c = i % 96;
  const int r = i / 96;
  xb[i] = f2bf((c < 83) ? x[(long)r * 83 + c] : 0.f);
}

__global__ void pe_kernel(const float* __restrict__ phase, float* __restrict__ pe_mod)
{
  const int i = blockIdx.x * 256 + threadIdx.x;
  if (i >= 128 * 384) return;
  const int d = i % 384, s = i / 384;
  float out = 0.f;
  if (d < 288) {
    const int pair = d >> 1;
    const float divv = expf((float)(2 * pair) * (-9.210340371976184f / 288.f));
    const float arg = (float)s * divv;
    const float v = (d & 1) ? cosf(arg) : sinf(arg);
    out = v * cosf(phase[d]);
  }
  pe_mod[i] = out;
}

// ---------------------------------------------------------------------------
extern "C" void kernel_launch(void* const* d_in, const int* in_sizes, int n_in,
                              void* d_out, int out_size, void* d_ws, size_t ws_size,
                              hipStream_t stream)
{
  (void)in_sizes; (void)n_in; (void)out_size;

  const float* x     = (const float*)d_in[0];
  const float* Wp    = (const float*)d_in[1];
  const float* bp    = (const float*)d_in[2];
  const float* phase = (const float*)d_in[3];
  const float* Wq    = (const float*)d_in[4];
  const float* bq    = (const float*)d_in[5];
  const float* Wk    = (const float*)d_in[6];
  const float* bk    = (const float*)d_in[7];
  const float* Wv    = (const float*)d_in[8];
  const float* bv    = (const float*)d_in[9];
  const float* Wo    = (const float*)d_in[10];
  const float* bo    = (const float*)d_in[11];
  const float* temp  = (const float*)d_in[12];
  const float* qscale= (const float*)d_in[13];
  const float* Wf1   = (const float*)d_in[14];
  const float* bf1   = (const float*)d_in[15];
  const float* Wf2   = (const float*)d_in[16];
  const float* bf2   = (const float*)d_in[17];
  const float* n1w   = (const float*)d_in[18];
  const float* n1b   = (const float*)d_in[19];
  const float* n2w   = (const float*)d_in[20];
  const float* n2b   = (const float*)d_in[21];
  const float* skip  = (const float*)d_in[22];
  const float* bn_w  = (const float*)d_in[23];
  const float* bn_b  = (const float*)d_in[24];
  const float* bn_mean=(const float*)d_in[25];
  const float* bn_var= (const float*)d_in[26];
  const float* h1w   = (const float*)d_in[27];
  const float* h1b   = (const float*)d_in[28];
  const float* h2w   = (const float*)d_in[29];
  const float* h2b   = (const float*)d_in[30];
  const float* h3w   = (const float*)d_in[31];
  const float* h3b   = (const float*)d_in[32];
  const float* u1w   = (const float*)d_in[33];
  const float* u1b   = (const float*)d_in[34];
  const float* u2w   = (const float*)d_in[35];
  const float* u2b   = (const float*)d_in[36];

  char* ws = (char*)d_ws;
  size_t off = 0;
  auto alloc = [&](size_t n) -> char* {
    off = (off + 255) & ~(size_t)255;
    char* p = ws + off;
    off += n;
    return p;
  };

  const long M = 131072;

  short* h_bf   = (short*)alloc((size_t)M * 288 * 2);
  float* pe_mod = (float*)alloc(128 * 384 * 4);

  short* Wp_b   = (short*)alloc((size_t)384 * 96 * 2);
  short* Wqkv_b = (short*)alloc((size_t)4 * 1152 * 288 * 2);
  short* Wo_b   = (short*)alloc((size_t)4 * 288 * 384 * 2);
  short* Wf1_b  = (short*)alloc((size_t)4 * 1408 * 288 * 2);
  short* Wf2_b  = (short*)alloc((size_t)4 * 384 * 1408 * 2);

  float* bp_p   = (float*)alloc((size_t)384 * 4);
  float* bqkv_p = (float*)alloc((size_t)4 * 1152 * 4);
  float* bo_p   = (float*)alloc((size_t)4 * 384 * 4);
  float* bf1_p  = (float*)alloc((size_t)4 * 1408 * 4);
  float* bf2_p  = (float*)alloc((size_t)4 * 384 * 4);

  const size_t fixed = off;
  int NC = 1;
  while (NC < 16 && fixed + (size_t)(M / NC) * 2304 + (1u << 20) > ws_size) NC <<= 1;
  const long Mc = M / NC;
  const long sec = Mc * 48;

  char* R = alloc((size_t)Mc * 2304);
  short* qkv_bf = (short*)R;                              // [24][Mc][48] head-major
  short* x_bfc  = (short*)R;                              // [Mc][96]

  const dim3 blk(256);

  auto conv_w = [&](const float* s, short* d, int N, int K, int Np, int Kp, int L) {
    const int total = L * Np * Kp;
    conv_w_kernel<<<dim3((total + 255) / 256), blk, 0, stream>>>(s, d, N, K, Np, Kp, total);
  };
  auto conv_b = [&](const float* s, float* d, int N, int Np, int L) {
    const int total = L * Np;
    conv_b_kernel<<<dim3((total + 255) / 256), blk, 0, stream>>>(s, d, N, Np, total);
  };
  conv_w(Wp,  Wp_b,  288,   83, 384,   96, 1);
  conv_wqkv_kernel<<<dim3((4 * 1152 * 288 + 255) / 256), blk, 0, stream>>>(Wq, Wk, Wv, temp, Wqkv_b);
  conv_wo_kernel<<<dim3((4 * 288 * 384 + 255) / 256), blk, 0, stream>>>(Wo, Wo_b);
  conv_w(Wf1, Wf1_b, 1315, 288, 1408, 288, 4);
  conv_w(Wf2, Wf2_b, 288, 1315, 384, 1408, 4);
  conv_b(bp,  bp_p,  288,  384, 1);
  conv_bqkv_kernel<<<dim3((4 * 1152 + 255) / 256), blk, 0, stream>>>(bq, bk, bv, temp, bqkv_p);
  conv_b(bo,  bo_p,  288,  384, 4);
  conv_b(bf1, bf1_p, 1315, 1408, 4);
  conv_b(bf2, bf2_p, 288,  384, 4);
  pe_kernel<<<dim3((128 * 384 + 255) / 256), blk, 0, stream>>>(phase, pe_mod);

  auto gemm = [&](int mode, const short* A, const short* Bmat, const float* bias,
                  short* C, const float* pe, int K, int lda, int ldb, int ldc,
                  int Nstore, int NT, long Mrows, long hstride) {
    const dim3 grid((unsigned)((Mrows / 128) * NT));
    switch (mode) {
      case 0: gemm_kernel<0><<<grid, blk, 0, stream>>>(A, Bmat, bias, C, pe, K, lda, ldb, ldc, Nstore, NT, hstride); break;
      case 1: gemm_kernel<1><<<grid, blk, 0, stream>>>(A, Bmat, bias, C, pe, K, lda, ldb, ldc, Nstore, NT, hstride); break;
      case 2: gemm_kernel<2><<<grid, blk, 0, stream>>>(A, Bmat, bias, C, pe, K, lda, ldb, ldc, Nstore, NT, hstride); break;
      default: gemm_kernel<3><<<grid, blk, 0, stream>>>(A, Bmat, bias, C, pe, K, lda, ldb, ldc, Nstore, NT, hstride); break;
    }
  };

  for (int c = 0; c < NC; ++c) {
    const float* x_c = x + (size_t)c * Mc * 83;
    short* h_c = h_bf + (size_t)c * Mc * 288;

    const int xtot = (int)(Mc * 96);
    conv_x_kernel<<<dim3((xtot + 255) / 256), blk, 0, stream>>>(x_c, x_bfc, xtot);

    gemm(2, x_bfc, Wp_b, bp_p, h_c, pe_mod, 96, 96, 96, 288, 288, 3, Mc, 0);

    for (int l = 0; l < 4; ++l) {
      const short* Wqkv_l = Wqkv_b + (size_t)l * 1152 * 288;
      const short* Wo_l   = Wo_b   + (size_t)l * 288 * 384;
      const short* Wf1_l  = Wf1_b  + (size_t)l * 1408 * 288;
      const short* Wf2_l  = Wf2_b  + (size_t)l * 384 * 1408;

      gemm(3, h_c, Wqkv_l, bqkv_p + l * 1152, qkv_bf, nullptr,
           288, 288, 288, 0, 1152, 9, Mc, sec);

      attn_kernel<<<dim3((unsigned)(Mc / 128), 8), blk, 0, stream>>>(
          qkv_bf, qscale, l, Mc);

      gemm_ln_kernel<true><<<dim3((unsigned)(Mc / 128)), dim3(512), 0, stream>>>(
          qkv_bf + 16 * sec, Wo_l, bo_p + l * 384, h_c, n1w + l * 288, n1b + l * 288,
          skip, l, 1, 384, 48, 384, sec);

      ffn_kernel<<<dim3((unsigned)(Mc / 128)), dim3(512), 0, stream>>>(
          h_c, Wf1_l, bf1_p + l * 1408, Wf2_l, bf2_p + l * 384,
          n2w + l * 288, n2b + l * 288);
    }
  }

  head_kernel<<<dim3(1024), blk, 0, stream>>>(h_bf, (float*)d_out,
      bn_w, bn_b, bn_mean, bn_var,
      h1w, h1b, h2w, h2b, h3w, h3b,
      u1w, u1b, u2w, u2b);
}

// Round 11
// 3060.513 us; speedup vs baseline: 1.1076x; 1.1076x over previous
//
#include <hip/hip_runtime.h>
#include <cstdint>

typedef __attribute__((ext_vector_type(8))) short short8;
typedef __attribute__((ext_vector_type(4))) short s4v;
typedef __attribute__((ext_vector_type(4))) float floatx4;

#define DEV __device__ __forceinline__

DEV short f2bf(float f) {
  unsigned u = __builtin_bit_cast(unsigned, f);
  u += 0x7fffu + ((u >> 16) & 1u);
  return (short)(u >> 16);
}
DEV short f2bf_ru(float f) {
  unsigned u = __builtin_bit_cast(unsigned, f);
  return (short)((u + 0x8000u) >> 16);
}
DEV float bf2f(short s) {
  unsigned u = ((unsigned)(unsigned short)s) << 16;
  return __builtin_bit_cast(float, u);
}
DEV float gelu_exact(float x) {
  return 0.5f * x * (1.0f + erff(x * 0.70710678118654752f));
}
DEV float gelu_fast(float x) {
  const float t2 = 1.5957691216057308f * (x + 0.044715f * x * x * x);
  return x / (1.0f + __expf(-t2));
}
DEV void gload16(const void* g, void* l) {
  __builtin_amdgcn_global_load_lds((const __attribute__((address_space(1))) void*)g,
                                   (__attribute__((address_space(3))) void*)l,
                                   16, 0, 0);
}

// ---------------------------------------------------------------------------
// 128x128-tile bf16 MFMA GEMM, swapped-operand epilogue.  BK=64 main ticks;
// each 64-slice stored as TWO 32-wide sub-slices in the proven XOR layout.
// MODE 0: C = v + bias ; MODE 1: gelu ; MODE 2: + pe ; MODE 3: head-major store
// ---------------------------------------------------------------------------
template<int MODE>
__global__ __launch_bounds__(256)
void gemm_kernel(const short* __restrict__ A, const short* __restrict__ Bw,
                 const float* __restrict__ bias, short* __restrict__ C,
                 const float* __restrict__ pe,
                 int K, int lda, int ldb, int ldc, int Nstore, int NT, long hstride)
{
  __shared__ __align__(16) short lds[128 * 136];
  short* Ct = lds;

  const int tid  = threadIdx.x;
  const int wave = tid >> 6, lane = tid & 63;
  const int quad = lane >> 4, r16 = lane & 15;
  const int per = gridDim.x >> 3;
  const int gti = (blockIdx.x & 7) * per + (blockIdx.x >> 3);
  const int mt = gti / NT, nt = gti - mt * NT;
  const int wm = (wave >> 1) * 64, wn = (wave & 1) * 64;

  const long Abase = (long)mt * 128 * lda;
  const long Bbase = (long)nt * 128 * ldb;

  floatx4 acc[4][4] = {};

  int k0 = 0;
  for (; k0 + 64 <= K; k0 += 64) {
    __syncthreads();
#pragma unroll
    for (int j = 0; j < 8; ++j) {
      const int c2 = tid + j * 256;      // [op(1)|half(1)|sub(9)]
      const int op = c2 >> 10;
      const int cb = c2 & 1023;
      const int half = cb >> 9;
      const int sub = cb & 511;
      const int row = sub >> 2, cc = (sub & 3) ^ ((row >> 1) & 3);
      const short* src = op ? (Bw + Bbase + (long)row * ldb + k0 + half * 32 + cc * 8)
                            : (A  + Abase + (long)row * lda + k0 + half * 32 + cc * 8);
      gload16(src, &lds[(size_t)(op * 8192 + half * 4096 + (sub & ~63) * 8)]);
    }
    __syncthreads();

#pragma unroll
    for (int s = 0; s < 2; ++s) {
      short8 af[4], bfr[4];
#pragma unroll
      for (int i = 0; i < 4; ++i) {
        const int R = wm + i * 16 + r16;
        af[i] = *(const short8*)&lds[s * 4096 + R * 32 + (quad ^ ((R >> 1) & 3)) * 8];
      }
#pragma unroll
      for (int j = 0; j < 4; ++j) {
        const int R = wn + j * 16 + r16;
        bfr[j] = *(const short8*)&lds[8192 + s * 4096 + R * 32 + (quad ^ ((R >> 1) & 3)) * 8];
      }
#pragma unroll
      for (int i = 0; i < 4; ++i)
#pragma unroll
        for (int j = 0; j < 4; ++j)
          acc[i][j] = __builtin_amdgcn_mfma_f32_16x16x32_bf16(bfr[j], af[i], acc[i][j], 0, 0, 0);
    }
  }

  if (k0 < K) {  // 32-wide tail
    short* As = lds;
    short* Bs = lds + 128 * 32;
    const int row0 = tid >> 2,         cc0 = (tid & 3) ^ ((row0 >> 1) & 3);
    const int row1 = (256 + tid) >> 2, cc1 = ((256 + tid) & 3) ^ ((row1 >> 1) & 3);
    __syncthreads();
    gload16(A  + Abase + (long)row0 * lda + k0 + cc0 * 8, &As[(0 * 256 + wave * 64) * 8]);
    gload16(A  + Abase + (long)row1 * lda + k0 + cc1 * 8, &As[(1 * 256 + wave * 64) * 8]);
    gload16(Bw + Bbase + (long)row0 * ldb + k0 + cc0 * 8, &Bs[(0 * 256 + wave * 64) * 8]);
    gload16(Bw + Bbase + (long)row1 * ldb + k0 + cc1 * 8, &Bs[(1 * 256 + wave * 64) * 8]);
    __syncthreads();

    short8 af[4], bfr[4];
#pragma unroll
    for (int i = 0; i < 4; ++i) {
      const int R = wm + i * 16 + r16;
      af[i] = *(const short8*)&As[R * 32 + (quad ^ ((R >> 1) & 3)) * 8];
    }
#pragma unroll
    for (int j = 0; j < 4; ++j) {
      const int R = wn + j * 16 + r16;
      bfr[j] = *(const short8*)&Bs[R * 32 + (quad ^ ((R >> 1) & 3)) * 8];
    }
#pragma unroll
    for (int i = 0; i < 4; ++i)
#pragma unroll
      for (int j = 0; j < 4; ++j)
        acc[i][j] = __builtin_amdgcn_mfma_f32_16x16x32_bf16(bfr[j], af[i], acc[i][j], 0, 0, 0);
  }

  const int mb0 = mt * 128, tb = nt * 128;

  __syncthreads();
#pragma unroll
  for (int j = 0; j < 4; ++j) {
    const int n0 = wn + j * 16 + quad * 4;
    const floatx4 b4 = *(const floatx4*)&bias[tb + n0];
#pragma unroll
    for (int i = 0; i < 4; ++i) {
      const int m = wm + i * 16 + r16;
      floatx4 v = acc[i][j] + b4;
      if (MODE == 1) {
#pragma unroll
        for (int rg = 0; rg < 4; ++rg) v[rg] = gelu_fast(v[rg]);
      }
      if (MODE == 2) {
        const floatx4 p4 = *(const floatx4*)&pe[((mb0 + m) & 127) * 384 + tb + n0];
        v = v + p4;
      }
      s4v o4;
#pragma unroll
      for (int rg = 0; rg < 4; ++rg) o4[rg] = f2bf_ru(v[rg]);
      *(s4v*)&Ct[m * 136 + n0] = o4;
    }
  }
  __syncthreads();

#pragma unroll
  for (int rr = 0; rr < 8; ++rr) {
    const int chunk = rr * 256 + tid;
    const int row = chunk >> 4, ch = chunk & 15;
    const int gcol = tb + ch * 8;
    if (MODE == 3) {
      const int g = gcol / 48, d0 = gcol - g * 48;
      *(short8*)(C + (long)g * hstride + (long)(mb0 + row) * 48 + d0) =
          *(const short8*)&Ct[row * 136 + ch * 8];
    } else if (gcol < Nstore) {
      *(short8*)(C + (long)(mb0 + row) * ldc + gcol) = *(const short8*)&Ct[row * 136 + ch * 8];
    }
  }
}

// ---------------------------------------------------------------------------
// Fused GEMM + residual + LayerNorm, N=288 exact.  M-tile 128, 512 threads.
// Wave-tile 32x144 (4m x 2n wave grid).  Used for the Wo projection.
// ---------------------------------------------------------------------------
template<bool AHEAD>
__global__ __launch_bounds__(512, 4)
void gemm_ln_kernel(const short* __restrict__ A, const short* __restrict__ Bw,
                    const float* __restrict__ bias, short* __restrict__ h,
                    const float* __restrict__ lnw, const float* __restrict__ lnb,
                    const float* __restrict__ skip_p, int layer, int use_skip,
                    int K, int lda, int ldb, long ahs)
{
  __shared__ __align__(16) short lds[128 * 296];
  __shared__ float redp[4][2][2][16];
  __shared__ float reds[4][2][2][16];
  short* Hs = lds;

  const int tid  = threadIdx.x;
  const int wave = tid >> 6, lane = tid & 63;
  const int quad = lane >> 4, r16 = lane & 15;
  const int wr = wave >> 1, wc = wave & 1;
  const int mt = blockIdx.x;
  const long mrow0 = (long)mt * 128;

  floatx4 acc[2][9] = {};

  auto stage = [&](short* buf, int k0) {
    for (int c = tid; c < 1664; c += 512) {
      const void* src;
      if (c < 512) {
        const int row = c >> 2, cc = (c & 3) ^ ((row >> 1) & 3);
        if (AHEAD) {
          const int kc = k0 + cc * 8;
          const int g = kc / 48, d = kc - g * 48;
          src = A + (long)g * ahs + (mrow0 + row) * 48 + d;
        } else {
          src = A + (mrow0 + row) * lda + k0 + cc * 8;
        }
      } else {
        const int cb = c - 512;
        const int row = cb >> 2, cc = (cb & 3) ^ ((row >> 1) & 3);
        src = Bw + (long)row * ldb + k0 + cc * 8;
      }
      gload16(src, &buf[(size_t)(c & ~63) * 8]);
    }
  };

  auto compute = [&](const short* buf) {
    const short* As_ = buf;
    const short* Bs_ = buf + 4096;
    const int Ra0 = wr * 32 + r16, Ra1 = Ra0 + 16;
    const short8 af0 = *(const short8*)&As_[Ra0 * 32 + (quad ^ ((Ra0 >> 1) & 3)) * 8];
    const short8 af1 = *(const short8*)&As_[Ra1 * 32 + (quad ^ ((Ra1 >> 1) & 3)) * 8];
#pragma unroll
    for (int t = 0; t < 9; ++t) {
      const int Rb = wc * 144 + t * 16 + r16;
      const short8 b = *(const short8*)&Bs_[Rb * 32 + (quad ^ ((Rb >> 1) & 3)) * 8];
      acc[0][t] = __builtin_amdgcn_mfma_f32_16x16x32_bf16(b, af0, acc[0][t], 0, 0, 0);
      acc[1][t] = __builtin_amdgcn_mfma_f32_16x16x32_bf16(b, af1, acc[1][t], 0, 0, 0);
    }
  };

  short* const B0 = lds;
  short* const B1 = lds + 13312;

  stage(B0, 0);
  __syncthreads();
  int k0 = 0;
  while (true) {
    if (k0 + 32 < K) stage(B1, k0 + 32);
    compute(B0);
    __syncthreads();
    k0 += 32;
    if (k0 >= K) break;
    if (k0 + 32 < K) stage(B0, k0 + 32);
    compute(B1);
    __syncthreads();
    k0 += 32;
    if (k0 >= K) break;
  }

  for (int c = tid; c < 4608; c += 512) {
    const int row = c / 36, ch = c - row * 36;
    *(short8*)&Hs[row * 296 + ch * 8] =
        *(const short8*)(h + (mrow0 + row) * 288 + ch * 8);
  }
  __syncthreads();

  const float skipv = use_skip ? skip_p[layer] : 1.0f;
  const int m0 = wr * 32 + r16, m1 = m0 + 16;

  float ps0 = 0.f, ss0 = 0.f, ps1 = 0.f, ss1 = 0.f;
#pragma unroll
  for (int t = 0; t < 9; ++t) {
    const int n0 = wc * 144 + t * 16 + quad * 4;
    const floatx4 b4 = *(const floatx4*)&bias[n0];
    const s4v h40 = *(const s4v*)&Hs[m0 * 296 + n0];
    const s4v h41 = *(const s4v*)&Hs[m1 * 296 + n0];
#pragma unroll
    for (int rg = 0; rg < 4; ++rg) {
      const float y0 = bf2f(h40[rg]) + skipv * (acc[0][t][rg] + b4[rg]);
      const float y1 = bf2f(h41[rg]) + skipv * (acc[1][t][rg] + b4[rg]);
      acc[0][t][rg] = y0; acc[1][t][rg] = y1;
      ps0 += y0; ss0 += y0 * y0;
      ps1 += y1; ss1 += y1 * y1;
    }
  }
  ps0 += __shfl_xor(ps0, 16); ps0 += __shfl_xor(ps0, 32);
  ss0 += __shfl_xor(ss0, 16); ss0 += __shfl_xor(ss0, 32);
  ps1 += __shfl_xor(ps1, 16); ps1 += __shfl_xor(ps1, 32);
  ss1 += __shfl_xor(ss1, 16); ss1 += __shfl_xor(ss1, 32);
  if (lane < 16) {
    redp[wr][wc][0][r16] = ps0; redp[wr][wc][1][r16] = ps1;
    reds[wr][wc][0][r16] = ss0; reds[wr][wc][1][r16] = ss1;
  }
  __syncthreads();
  const float psum0 = redp[wr][0][0][r16] + redp[wr][1][0][r16];
  const float psum1 = redp[wr][0][1][r16] + redp[wr][1][1][r16];
  const float ssum0 = reds[wr][0][0][r16] + reds[wr][1][0][r16];
  const float ssum1 = reds[wr][0][1][r16] + reds[wr][1][1][r16];
  const float mean0 = psum0 * (1.f / 288.f), mean1 = psum1 * (1.f / 288.f);
  const float rstd0 = rsqrtf(ssum0 * (1.f / 288.f) - mean0 * mean0 + 1e-5f);
  const float rstd1 = rsqrtf(ssum1 * (1.f / 288.f) - mean1 * mean1 + 1e-5f);

#pragma unroll
  for (int t = 0; t < 9; ++t) {
    const int n0 = wc * 144 + t * 16 + quad * 4;
    const floatx4 w4 = *(const floatx4*)&lnw[n0];
    const floatx4 l4 = *(const floatx4*)&lnb[n0];
    s4v o0, o1;
#pragma unroll
    for (int rg = 0; rg < 4; ++rg) {
      o0[rg] = f2bf_ru((acc[0][t][rg] - mean0) * rstd0 * w4[rg] + l4[rg]);
      o1[rg] = f2bf_ru((acc[1][t][rg] - mean1) * rstd1 * w4[rg] + l4[rg]);
    }
    *(s4v*)&Hs[m0 * 296 + n0] = o0;
    *(s4v*)&Hs[m1 * 296 + n0] = o1;
  }
  __syncthreads();

  for (int c = tid; c < 4608; c += 512) {
    const int row = c / 36, ch = c - row * 36;
    *(short8*)(h + (mrow0 + row) * 288 + ch * 8) =
        *(const short8*)&Hs[row * 296 + ch * 8];
  }
}

// ---------------------------------------------------------------------------
// FUSED FFN, M-tile 128, 512 threads, wave-tile 32x144, FIVE ticks per chunk:
//   A: G1 k0-127   | stage W1 k128-255
//   B: G1 k128-255 | stage W1 tail32
//   C: G1 tail+gelu->f | stage W2 k0-63
//   D: G2 ks0,1    | stage W2 k64-127
//   E: G2 ks2,3    | stage next W1 k0-127
// Ring 2x18432 shorts (36KB) + f 16384 shorts (32KB) = 106KB, 1 blk/CU.
// ---------------------------------------------------------------------------
__global__ __launch_bounds__(512, 2)
void ffn_kernel(short* __restrict__ h,
                const short* __restrict__ W1, const float* __restrict__ b1,
                const short* __restrict__ W2, const float* __restrict__ b2,
                const float* __restrict__ lnw, const float* __restrict__ lnb)
{
  __shared__ __align__(16) short lds[53248];   // ring 2x18432 + f 16384
  __shared__ float redp[4][2][2][16];
  __shared__ float reds[4][2][2][16];
  short* const fl = lds + 36864;               // f: [4 ks][128 m][32]

  const int tid  = threadIdx.x;
  const int wave = tid >> 6, lane = tid & 63;
  const int quad = lane >> 4, r16 = lane & 15;
  const int wr = wave >> 1, wp = wave & 1;
  const long mrow0 = (long)blockIdx.x * 128;

  // persist h A-fragments across chunks (chunk-invariant)
  short8 ha[2][9];
#pragma unroll
  for (int i = 0; i < 2; ++i) {
    const long rb = (mrow0 + wr * 32 + i * 16 + r16) * 288L;
#pragma unroll
    for (int k9 = 0; k9 < 9; ++k9)
      ha[i][k9] = *(const short8*)(h + rb + k9 * 32 + quad * 8);
  }

  floatx4 acc2[2][9] = {};

  // stage W1 [c*128..+128) x k[kb..kb+128) as four 32-wide sub-slices
  auto stageW1_128 = [&](int c, int kb, short* dst) {
#pragma unroll
    for (int j = 0; j < 4; ++j) {
      const int c2t = tid + j * 512;
      const int s = c2t >> 9, c2 = c2t & 511;
      const int row = c2 >> 2, cc = (c2 & 3) ^ ((row >> 1) & 3);
      gload16(W1 + ((long)(c * 128 + row)) * 288 + kb + s * 32 + cc * 8,
              &dst[(size_t)(s * 4096 + (c2 & ~63) * 8)]);
    }
  };
  auto stageW1_32 = [&](int c, short* dst) {           // k = 256..288 tail
    const int row = tid >> 2, cc = (tid & 3) ^ ((row >> 1) & 3);
    gload16(W1 + ((long)(c * 128 + row)) * 288 + 256 + cc * 8,
            &dst[(size_t)(tid & ~63) * 8]);
  };
  // stage W2 [0..288) x k[kb..kb+64) as two 288x32 sub-slices
  auto stageW2_64 = [&](int c, int kb, short* dst) {
    for (int c2t = tid; c2t < 2304; c2t += 512) {
      const int s = (c2t >= 1152) ? 1 : 0;
      const int c2 = c2t - s * 1152;
      const int row = c2 >> 2, cc = (c2 & 3) ^ ((row >> 1) & 3);
      gload16(W2 + (long)row * 1408 + c * 128 + kb + s * 32 + cc * 8,
              &dst[(size_t)(s * 9216 + (c2 & ~63) * 8)]);
    }
  };

  short* const ring0 = lds;
  short* const ring1 = lds + 18432;

  stageW1_128(0, 0, ring0);
  __syncthreads();
  int cur = 0;

  for (int c = 0; c < 11; ++c) {
    floatx4 acc1[2][4] = {};

    // G1 over a staged k128 slice (4 sub-slices), ha indices hb..hb+3
    auto g1_128 = [&](const short* Sc, int hb) {
#pragma unroll
      for (int s = 0; s < 4; ++s) {
        short8 bfr[4];
#pragma unroll
        for (int j = 0; j < 4; ++j) {
          const int R = wp * 64 + j * 16 + r16;
          bfr[j] = *(const short8*)&Sc[s * 4096 + R * 32 + (quad ^ ((R >> 1) & 3)) * 8];
        }
#pragma unroll
        for (int i = 0; i < 2; ++i)
#pragma unroll
          for (int j = 0; j < 4; ++j)
            acc1[i][j] = __builtin_amdgcn_mfma_f32_16x16x32_bf16(bfr[j], ha[i][hb + s], acc1[i][j], 0, 0, 0);
      }
    };

    // ---- tick A ----
    {
      short* const Sn = cur ? ring0 : ring1;
      const short* Sc = cur ? ring1 : ring0;
      stageW1_128(c, 128, Sn);
      g1_128(Sc, 0);
      __syncthreads();
      cur ^= 1;
    }
    // ---- tick B ----
    {
      short* const Sn = cur ? ring0 : ring1;
      const short* Sc = cur ? ring1 : ring0;
      stageW1_32(c, Sn);
      g1_128(Sc, 4);
      __syncthreads();
      cur ^= 1;
    }
    // ---- tick C: tail + gelu -> f ----
    {
      short* const Sn = cur ? ring0 : ring1;
      const short* Sc = cur ? ring1 : ring0;
      stageW2_64(c, 0, Sn);

      short8 bfr[4];
#pragma unroll
      for (int j = 0; j < 4; ++j) {
        const int R = wp * 64 + j * 16 + r16;
        bfr[j] = *(const short8*)&Sc[R * 32 + (quad ^ ((R >> 1) & 3)) * 8];
      }
#pragma unroll
      for (int i = 0; i < 2; ++i)
#pragma unroll
        for (int j = 0; j < 4; ++j)
          acc1[i][j] = __builtin_amdgcn_mfma_f32_16x16x32_bf16(bfr[j], ha[i][8], acc1[i][j], 0, 0, 0);

      // f write in the proven MFMA-staged layout
#pragma unroll
      for (int i = 0; i < 2; ++i) {
        const int m = wr * 32 + i * 16 + r16;
#pragma unroll
        for (int j = 0; j < 4; ++j) {
          const int nb = c * 128 + wp * 64 + j * 16 + quad * 4;
          const floatx4 b4 = *(const floatx4*)&b1[nb];
          s4v o;
#pragma unroll
          for (int rg = 0; rg < 4; ++rg)
            o[rg] = f2bf_ru(gelu_fast(acc1[i][j][rg] + b4[rg]));
          const int ks = wp * 2 + (j >> 1);
          const int mg = ((j & 1) * 2 + (quad >> 1)) ^ ((m >> 1) & 3);
          *(s4v*)&fl[ks * 4096 + m * 32 + mg * 8 + (quad & 1) * 4] = o;
        }
      }
      __syncthreads();
      cur ^= 1;
    }
    // ---- ticks D, E: G2 over W2 k64 slices ----
#pragma unroll
    for (int g2t = 0; g2t < 2; ++g2t) {
      short* const Sn = cur ? ring0 : ring1;
      const short* Sc = cur ? ring1 : ring0;
      if (g2t == 0)    stageW2_64(c, 64, Sn);
      else if (c < 10) stageW1_128(c + 1, 0, Sn);

#pragma unroll
      for (int s = 0; s < 2; ++s) {
        const int ks = g2t * 2 + s;
        short8 af2[2];
#pragma unroll
        for (int i = 0; i < 2; ++i) {
          const int R = wr * 32 + i * 16 + r16;
          af2[i] = *(const short8*)&fl[ks * 4096 + R * 32 + (quad ^ ((R >> 1) & 3)) * 8];
        }
        short8 br[9];
#pragma unroll
        for (int t = 0; t < 9; ++t) {
          const int R = wp * 144 + t * 16 + r16;
          br[t] = *(const short8*)&Sc[s * 9216 + R * 32 + (quad ^ ((R >> 1) & 3)) * 8];
        }
#pragma unroll
        for (int i = 0; i < 2; ++i)
#pragma unroll
          for (int t = 0; t < 9; ++t)
            acc2[i][t] = __builtin_amdgcn_mfma_f32_16x16x32_bf16(br[t], af2[i], acc2[i][t], 0, 0, 0);
      }
      __syncthreads();
      cur ^= 1;
    }
  }

  // ---- residual + LayerNorm epilogue (128 rows) ----
  for (int c2 = tid; c2 < 4608; c2 += 512) {
    const int row = c2 / 36, ch = c2 - row * 36;
    *(short8*)&lds[row * 296 + ch * 8] =
        *(const short8*)(h + (mrow0 + row) * 288 + ch * 8);
  }
  __syncthreads();

  const int m0 = wr * 32 + r16, m1 = m0 + 16;
  float ps0 = 0.f, ss0 = 0.f, ps1 = 0.f, ss1 = 0.f;
#pragma unroll
  for (int t = 0; t < 9; ++t) {
    const int n0 = wp * 144 + t * 16 + quad * 4;
    const floatx4 b4 = *(const floatx4*)&b2[n0];
    const s4v h40 = *(const s4v*)&lds[m0 * 296 + n0];
    const s4v h41 = *(const s4v*)&lds[m1 * 296 + n0];
#pragma unroll
    for (int rg = 0; rg < 4; ++rg) {
      const float y0 = bf2f(h40[rg]) + acc2[0][t][rg] + b4[rg];
      const float y1 = bf2f(h41[rg]) + acc2[1][t][rg] + b4[rg];
      acc2[0][t][rg] = y0; acc2[1][t][rg] = y1;
      ps0 += y0; ss0 += y0 * y0;
      ps1 += y1; ss1 += y1 * y1;
    }
  }
  ps0 += __shfl_xor(ps0, 16); ps0 += __shfl_xor(ps0, 32);
  ss0 += __shfl_xor(ss0, 16); ss0 += __shfl_xor(ss0, 32);
  ps1 += __shfl_xor(ps1, 16); ps1 += __shfl_xor(ps1, 32);
  ss1 += __shfl_xor(ss1, 16); ss1 += __shfl_xor(ss1, 32);
  if (lane < 16) {
    redp[wr][wp][0][r16] = ps0; redp[wr][wp][1][r16] = ps1;
    reds[wr][wp][0][r16] = ss0; reds[wr][wp][1][r16] = ss1;
  }
  __syncthreads();
  const float psum0 = redp[wr][0][0][r16] + redp[wr][1][0][r16];
  const float psum1 = redp[wr][0][1][r16] + redp[wr][1][1][r16];
  const float ssum0 = reds[wr][0][0][r16] + reds[wr][1][0][r16];
  const float ssum1 = reds[wr][0][1][r16] + reds[wr][1][1][r16];
  const float mean0 = psum0 * (1.f / 288.f), mean1 = psum1 * (1.f / 288.f);
  const float rstd0 = rsqrtf(ssum0 * (1.f / 288.f) - mean0 * mean0 + 1e-5f);
  const float rstd1 = rsqrtf(ssum1 * (1.f / 288.f) - mean1 * mean1 + 1e-5f);

#pragma unroll
  for (int t = 0; t < 9; ++t) {
    const int n0 = wp * 144 + t * 16 + quad * 4;
    const floatx4 w4 = *(const floatx4*)&lnw[n0];
    const floatx4 l4 = *(const floatx4*)&lnb[n0];
    s4v o0, o1;
#pragma unroll
    for (int rg = 0; rg < 4; ++rg) {
      o0[rg] = f2bf_ru((acc2[0][t][rg] - mean0) * rstd0 * w4[rg] + l4[rg]);
      o1[rg] = f2bf_ru((acc2[1][t][rg] - mean1) * rstd1 * w4[rg] + l4[rg]);
    }
    *(s4v*)&lds[m0 * 296 + n0] = o0;
    *(s4v*)&lds[m1 * 296 + n0] = o1;
  }
  __syncthreads();

  for (int c2 = tid; c2 < 4608; c2 += 512) {
    const int row = c2 / 36, ch = c2 - row * 36;
    *(short8*)(h + (mrow0 + row) * 288 + ch * 8) =
        *(const short8*)&lds[row * 296 + ch * 8];
  }
}

// ---------------------------------------------------------------------------
// Attention.  qkv head-major [24][Mc][48]; q pre-scaled by 1/(sqrt(41)*temp)
// at weight conversion.
// ---------------------------------------------------------------------------
__global__ __launch_bounds__(256)
void attn_kernel(short* __restrict__ qkv,
                 const float* __restrict__ qscale, int layer, long Mc)
{
  __shared__ __align__(16) short qk[2 * 128 * 72];   // qs|ks, later Pb[128][136]
  __shared__ __align__(16) short vsT[48 * 136 + 32]; // [d][s], skew ((d>>3)&3)*8
  __shared__ float red[2][2][64];

  short* qs = qk;
  short* ks = qk + 128 * 72;
  short* Pb = qk;

  const int b = blockIdx.x, h = blockIdx.y;
  const int tid = threadIdx.x;
  const long sec = Mc * 48;
  const short* qg = qkv + (long)h * sec + (long)b * 128 * 48;
  const short* kg = qg + 8 * sec;
  const short* vg = qg + 16 * sec;
  short* og = qkv + (long)(16 + h) * sec + (long)b * 128 * 48;

  for (int c = tid; c < 768; c += 256) {
    const int s = c / 6, dc = c - (c / 6) * 6;
    *(short8*)&qs[s * 72 + dc * 8] = *(const short8*)(qg + (long)s * 48 + dc * 8);
    *(short8*)&ks[s * 72 + dc * 8] = *(const short8*)(kg + (long)s * 48 + dc * 8);
  }
  {
    short8 z;
#pragma unroll
    for (int j = 0; j < 8; ++j) z[j] = 0;
    for (int c = tid; c < 384; c += 256) {
      const int s = c / 3, t = c - (c / 3) * 3;
      *(short8*)&qs[s * 72 + 48 + t * 8] = z;
      *(short8*)&ks[s * 72 + 48 + t * 8] = z;
    }
  }
  for (int c = tid; c < 768; c += 256) {
    const int s = c & 127, dc = c >> 7;
    const short8 tv = *(const short8*)(vg + (long)s * 48 + dc * 8);
#pragma unroll
    for (int j = 0; j < 8; ++j) {
      const int row = dc * 8 + j;
      vsT[row * 136 + ((row >> 3) & 3) * 8 + s] = tv[j];
    }
  }
  __syncthreads();

  const int wave = tid >> 6, lane = tid & 63;
  const int quad = lane >> 4, r16 = lane & 15;
  const int wm = (wave >> 1) * 64, wn = (wave & 1) * 64;
  const int rh = wave >> 1, ch = wave & 1;
  const float qsc = qscale[layer * 8 + h];

  floatx4 acc[4][4] = {};
#pragma unroll
  for (int kk = 0; kk < 2; ++kk) {
    const int k0 = kk * 32;
    short8 af[4], bfr[4];
#pragma unroll
    for (int i = 0; i < 4; ++i)
      af[i] = *(const short8*)&qs[(wm + i * 16 + r16) * 72 + k0 + quad * 8];
#pragma unroll
    for (int j = 0; j < 4; ++j)
      bfr[j] = *(const short8*)&ks[(wn + j * 16 + r16) * 72 + k0 + quad * 8];
#pragma unroll
    for (int i = 0; i < 4; ++i)
#pragma unroll
      for (int j = 0; j < 4; ++j)
        acc[i][j] = __builtin_amdgcn_mfma_f32_16x16x32_bf16(bfr[j], af[i], acc[i][j], 0, 0, 0);
  }

  float rmax[4], rsum[4];
#pragma unroll
  for (int i = 0; i < 4; ++i) {
    float m = acc[i][0][0];
#pragma unroll
    for (int j = 0; j < 4; ++j)
#pragma unroll
      for (int rg = 0; rg < 4; ++rg) m = fmaxf(m, acc[i][j][rg]);
    m = fmaxf(m, __shfl_xor(m, 16));
    m = fmaxf(m, __shfl_xor(m, 32));
    rmax[i] = m;
  }
  if (lane < 16)
#pragma unroll
    for (int i = 0; i < 4; ++i) red[rh][ch][i * 16 + r16] = rmax[i];
  __syncthreads();
#pragma unroll
  for (int i = 0; i < 4; ++i)
    rmax[i] = fmaxf(red[rh][0][i * 16 + r16], red[rh][1][i * 16 + r16]);

#pragma unroll
  for (int i = 0; i < 4; ++i) {
    float s = 0.f;
#pragma unroll
    for (int j = 0; j < 4; ++j)
#pragma unroll
      for (int rg = 0; rg < 4; ++rg) {
        const float e = __expf(acc[i][j][rg] - rmax[i]);
        acc[i][j][rg] = e;
        s += e;
      }
    s += __shfl_xor(s, 16);
    s += __shfl_xor(s, 32);
    rsum[i] = s;
  }
  __syncthreads();
  if (lane < 16)
#pragma unroll
    for (int i = 0; i < 4; ++i) red[rh][ch][i * 16 + r16] = rsum[i];
  __syncthreads();
#pragma unroll
  for (int i = 0; i < 4; ++i)
    rmax[i] = qsc / (red[rh][0][i * 16 + r16] + red[rh][1][i * 16 + r16]);

#pragma unroll
  for (int i = 0; i < 4; ++i) {
    const int sq = wm + i * 16 + r16;
#pragma unroll
    for (int j = 0; j < 4; ++j) {
      const int sk0 = wn + j * 16 + quad * 4;
      s4v p4;
#pragma unroll
      for (int rg = 0; rg < 4; ++rg) p4[rg] = f2bf_ru(acc[i][j][rg] * rmax[i]);
      *(s4v*)&Pb[sq * 136 + sk0] = p4;
    }
  }
  __syncthreads();

  const int om = (wave >> 1) * 64, on = (wave & 1) * 32;
  const int jn = (on == 0) ? 2 : 1;
  floatx4 oacc[4][2] = {};
  for (int kk = 0; kk < 4; ++kk) {
    const int k0 = kk * 32;
    short8 af[4], bfr[2];
#pragma unroll
    for (int i = 0; i < 4; ++i)
      af[i] = *(const short8*)&Pb[(om + i * 16 + r16) * 136 + k0 + quad * 8];
    for (int j = 0; j < jn; ++j) {
      const int row = on + j * 16 + r16;
      bfr[j] = *(const short8*)&vsT[row * 136 + ((row >> 3) & 3) * 8 + k0 + quad * 8];
    }
#pragma unroll
    for (int i = 0; i < 4; ++i)
      for (int j = 0; j < jn; ++j)
        oacc[i][j] = __builtin_amdgcn_mfma_f32_16x16x32_bf16(bfr[j], af[i], oacc[i][j], 0, 0, 0);
  }
#pragma unroll
  for (int i = 0; i < 4; ++i)
    for (int j = 0; j < jn; ++j) {
      const int d0 = on + j * 16 + quad * 4;
      const int sq = om + i * 16 + r16;
      s4v o4;
#pragma unroll
      for (int rg = 0; rg < 4; ++rg) o4[rg] = f2bf_ru(oacc[i][j][rg]);
      *(s4v*)(og + (long)sq * 48 + d0) = o4;
    }
}

// ---------------------------------------------------------------------------
// Pool over S + BN + GELU MLP head + uncertainty head.  Block per b.
// ---------------------------------------------------------------------------
__global__ __launch_bounds__(256)
void head_kernel(const short* __restrict__ hb, float* __restrict__ out,
                 const float* bn_w, const float* bn_b, const float* bn_mean, const float* bn_var,
                 const float* h1w, const float* h1b, const float* h2w, const float* h2b,
                 const float* h3w, const float* h3b,
                 const float* u1w, const float* u1b, const float* u2w, const float* u2b)
{
  __shared__ float psum[252][8];
  __shared__ float pooled[288], z[288], z1[144], z2[72], uu[72];
  const int b = blockIdx.x, tid = threadIdx.x;

  if (tid < 252) {
    const int cch = tid % 36, grp = tid / 36;
    float a[8];
#pragma unroll
    for (int j = 0; j < 8; ++j) a[j] = 0.f;
    for (int r = grp; r < 128; r += 7) {
      const short8 hv = *(const short8*)(hb + ((long)b * 128 + r) * 288 + cch * 8);
#pragma unroll
      for (int j = 0; j < 8; ++j) a[j] += bf2f(hv[j]);
    }
#pragma unroll
    for (int j = 0; j < 8; ++j) psum[tid][j] = a[j];
  }
  __syncthreads();
  for (int d = tid; d < 288; d += 256) {
    const int cch = d >> 3, j = d & 7;
    float s = 0.f;
#pragma unroll
    for (int g = 0; g < 7; ++g) s += psum[g * 36 + cch][j];
    pooled[d] = s * (1.f / 128.f);
  }
  __syncthreads();

  for (int d = tid; d < 288; d += 256) {
    const float p = pooled[d];
    z[d] = gelu_exact((p - bn_mean[d]) * rsqrtf(bn_var[d] + 1e-5f) * bn_w[d] + bn_b[d]);
  }
  __syncthreads();

  if (tid < 144) {
    float s = h1b[tid];
    for (int k = 0; k < 288; ++k) s += z[k] * h1w[tid * 288 + k];
    z1[tid] = gelu_exact(s);
  } else if (tid < 216) {
    const int t = tid - 144;
    float s = u1b[t];
    for (int k = 0; k < 288; ++k) s += pooled[k] * u1w[t * 288 + k];
    uu[t] = fmaxf(s, 0.f);
  }
  __syncthreads();

  if (tid < 72) {
    float s = h2b[tid];
    for (int k = 0; k < 144; ++k) s += z1[k] * h2w[tid * 144 + k];
    z2[tid] = gelu_exact(s);
  }
  __syncthreads();

  if (tid == 0) {
    float s = h3b[0];
    for (int k = 0; k < 72; ++k) s += z2[k] * h3w[k];
    out[b] = s;
  }
  if (tid == 64) {
    float s = u2b[0];
    for (int k = 0; k < 72; ++k) s += uu[k] * u2w[k];
    out[1024 + b] = (s > 20.f) ? s : log1pf(__expf(s));
  }
}

// ---------------------------------------------------------------------------
// Conversion / padding kernels
// ---------------------------------------------------------------------------
__global__ void conv_w_kernel(const float* __restrict__ src, short* __restrict__ dst,
                              int N, int K, int Npad, int Kpad, int total)
{
  const int i = blockIdx.x * 256 + threadIdx.x;
  if (i >= total) return;
  const int kk = i % Kpad;
  const int t  = i / Kpad;
  const int n  = t % Npad;
  const int l  = t / Npad;
  const float v = (n < N && kk < K) ? src[((long)l * N + n) * K + kk] : 0.f;
  dst[i] = f2bf(v);
}

__global__ void conv_b_kernel(const float* __restrict__ src, float* __restrict__ dst,
                              int N, int Npad, int total)
{
  const int i = blockIdx.x * 256 + threadIdx.x;
  if (i >= total) return;
  const int n = i % Npad, l = i / Npad;
  dst[i] = (n < N) ? src[l * N + n] : 0.f;
}

// q-section (sec==0) pre-scaled by 1/(sqrt(41)*temp[l])
__global__ void conv_wqkv_kernel(const float* __restrict__ Wq, const float* __restrict__ Wk,
                                 const float* __restrict__ Wv, const float* __restrict__ temp,
                                 short* __restrict__ dst)
{
  const int i = blockIdx.x * 256 + threadIdx.x;
  if (i >= 4 * 1152 * 288) return;
  const int kk = i % 288;
  const int t  = i / 288;
  const int r  = t % 1152;
  const int l  = t / 1152;
  const int g  = r / 48, d = r - (r / 48) * 48;
  const int sec = g >> 3, head = g & 7;
  float v = 0.f;
  if (d < 41) {
    const float* W = (sec == 0) ? Wq : (sec == 1) ? Wk : Wv;
    v = W[((long)l * 328 + head * 41 + d) * 288 + kk];
    if (sec == 0) v *= 1.0f / (6.4031242374328485f * temp[l]);
  }
  dst[i] = f2bf(v);
}

__global__ void conv_bqkv_kernel(const float* __restrict__ bq, const float* __restrict__ bk,
                                 const float* __restrict__ bv, const float* __restrict__ temp,
                                 float* __restrict__ dst)
{
  const int i = blockIdx.x * 256 + threadIdx.x;
  if (i >= 4 * 1152) return;
  const int r = i % 1152, l = i / 1152;
  const int g = r / 48, d = r - (r / 48) * 48;
  const int sec = g >> 3, head = g & 7;
  float v = 0.f;
  if (d < 41) {
    const float* b = (sec == 0) ? bq : (sec == 1) ? bk : bv;
    v = b[l * 328 + head * 41 + d];
    if (sec == 0) v *= 1.0f / (6.4031242374328485f * temp[l]);
  }
  dst[i] = v;
}

__global__ void conv_wo_kernel(const float* __restrict__ Wo, short* __restrict__ dst)
{
  const int i = blockIdx.x * 256 + threadIdx.x;
  if (i >= 4 * 288 * 384) return;
  const int kk = i % 384;
  const int t  = i / 384;
  const int n  = t % 288;
  const int l  = t / 288;
  const int head = kk / 48, d = kk - head * 48;
  float v = 0.f;
  if (d < 41) v = Wo[((long)l * 288 + n) * 328 + head * 41 + d];
  dst[i] = f2bf(v);
}

__global__ void conv_x_kernel(const float* __restrict__ x, short* __restrict__ xb, int total)
{
  const int i = blockIdx.x * 256 + threadIdx.x;
  if (i >= total) return;
  const int c = i % 96;
  const int r = i / 96;
  xb[i] = f2bf((c < 83) ? x[(long)r * 83 + c] : 0.f);
}

__global__ void pe_kernel(const float* __restrict__ phase, float* __restrict__ pe_mod)
{
  const int i = blockIdx.x * 256 + threadIdx.x;
  if (i >= 128 * 384) return;
  const int d = i % 384, s = i / 384;
  float out = 0.f;
  if (d < 288) {
    const int pair = d >> 1;
    const float divv = expf((float)(2 * pair) * (-9.210340371976184f / 288.f));
    const float arg = (float)s * divv;
    const float v = (d & 1) ? cosf(arg) : sinf(arg);
    out = v * cosf(phase[d]);
  }
  pe_mod[i] = out;
}

// ---------------------------------------------------------------------------
extern "C" void kernel_launch(void* const* d_in, const int* in_sizes, int n_in,
                              void* d_out, int out_size, void* d_ws, size_t ws_size,
                              hipStream_t stream)
{
  (void)in_sizes; (void)n_in; (void)out_size;

  const float* x     = (const float*)d_in[0];
  const float* Wp    = (const float*)d_in[1];
  const float* bp    = (const float*)d_in[2];
  const float* phase = (const float*)d_in[3];
  const float* Wq    = (const float*)d_in[4];
  const float* bq    = (const float*)d_in[5];
  const float* Wk    = (const float*)d_in[6];
  const float* bk    = (const float*)d_in[7];
  const float* Wv    = (const float*)d_in[8];
  const float* bv    = (const float*)d_in[9];
  const float* Wo    = (const float*)d_in[10];
  const float* bo    = (const float*)d_in[11];
  const float* temp  = (const float*)d_in[12];
  const float* qscale= (const float*)d_in[13];
  const float* Wf1   = (const float*)d_in[14];
  const float* bf1   = (const float*)d_in[15];
  const float* Wf2   = (const float*)d_in[16];
  const float* bf2   = (const float*)d_in[17];
  const float* n1w   = (const float*)d_in[18];
  const float* n1b   = (const float*)d_in[19];
  const float* n2w   = (const float*)d_in[20];
  const float* n2b   = (const float*)d_in[21];
  const float* skip  = (const float*)d_in[22];
  const float* bn_w  = (const float*)d_in[23];
  const float* bn_b  = (const float*)d_in[24];
  const float* bn_mean=(const float*)d_in[25];
  const float* bn_var= (const float*)d_in[26];
  const float* h1w   = (const float*)d_in[27];
  const float* h1b   = (const float*)d_in[28];
  const float* h2w   = (const float*)d_in[29];
  const float* h2b   = (const float*)d_in[30];
  const float* h3w   = (const float*)d_in[31];
  const float* h3b   = (const float*)d_in[32];
  const float* u1w   = (const float*)d_in[33];
  const float* u1b   = (const float*)d_in[34];
  const float* u2w   = (const float*)d_in[35];
  const float* u2b   = (const float*)d_in[36];

  char* ws = (char*)d_ws;
  size_t off = 0;
  auto alloc = [&](size_t n) -> char* {
    off = (off + 255) & ~(size_t)255;
    char* p = ws + off;
    off += n;
    return p;
  };

  const long M = 131072;

  short* h_bf   = (short*)alloc((size_t)M * 288 * 2);
  float* pe_mod = (float*)alloc(128 * 384 * 4);

  short* Wp_b   = (short*)alloc((size_t)384 * 96 * 2);
  short* Wqkv_b = (short*)alloc((size_t)4 * 1152 * 288 * 2);
  short* Wo_b   = (short*)alloc((size_t)4 * 288 * 384 * 2);
  short* Wf1_b  = (short*)alloc((size_t)4 * 1408 * 288 * 2);
  short* Wf2_b  = (short*)alloc((size_t)4 * 384 * 1408 * 2);

  float* bp_p   = (float*)alloc((size_t)384 * 4);
  float* bqkv_p = (float*)alloc((size_t)4 * 1152 * 4);
  float* bo_p   = (float*)alloc((size_t)4 * 384 * 4);
  float* bf1_p  = (float*)alloc((size_t)4 * 1408 * 4);
  float* bf2_p  = (float*)alloc((size_t)4 * 384 * 4);

  const size_t fixed = off;
  int NC = 1;
  while (NC < 16 && fixed + (size_t)(M / NC) * 2304 + (1u << 20) > ws_size) NC <<= 1;
  const long Mc = M / NC;
  const long sec = Mc * 48;

  char* R = alloc((size_t)Mc * 2304);
  short* qkv_bf = (short*)R;                              // [24][Mc][48] head-major
  short* x_bfc  = (short*)R;                              // [Mc][96]

  const dim3 blk(256);

  auto conv_w = [&](const float* s, short* d, int N, int K, int Np, int Kp, int L) {
    const int total = L * Np * Kp;
    conv_w_kernel<<<dim3((total + 255) / 256), blk, 0, stream>>>(s, d, N, K, Np, Kp, total);
  };
  auto conv_b = [&](const float* s, float* d, int N, int Np, int L) {
    const int total = L * Np;
    conv_b_kernel<<<dim3((total + 255) / 256), blk, 0, stream>>>(s, d, N, Np, total);
  };
  conv_w(Wp,  Wp_b,  288,   83, 384,   96, 1);
  conv_wqkv_kernel<<<dim3((4 * 1152 * 288 + 255) / 256), blk, 0, stream>>>(Wq, Wk, Wv, temp, Wqkv_b);
  conv_wo_kernel<<<dim3((4 * 288 * 384 + 255) / 256), blk, 0, stream>>>(Wo, Wo_b);
  conv_w(Wf1, Wf1_b, 1315, 288, 1408, 288, 4);
  conv_w(Wf2, Wf2_b, 288, 1315, 384, 1408, 4);
  conv_b(bp,  bp_p,  288,  384, 1);
  conv_bqkv_kernel<<<dim3((4 * 1152 + 255) / 256), blk, 0, stream>>>(bq, bk, bv, temp, bqkv_p);
  conv_b(bo,  bo_p,  288,  384, 4);
  conv_b(bf1, bf1_p, 1315, 1408, 4);
  conv_b(bf2, bf2_p, 288,  384, 4);
  pe_kernel<<<dim3((128 * 384 + 255) / 256), blk, 0, stream>>>(phase, pe_mod);

  auto gemm = [&](int mode, const short* A, const short* Bmat, const float* bias,
                  short* C, const float* pe, int K, int lda, int ldb, int ldc,
                  int Nstore, int NT, long Mrows, long hstride) {
    const dim3 grid((unsigned)((Mrows / 128) * NT));
    switch (mode) {
      case 0: gemm_kernel<0><<<grid, blk, 0, stream>>>(A, Bmat, bias, C, pe, K, lda, ldb, ldc, Nstore, NT, hstride); break;
      case 1: gemm_kernel<1><<<grid, blk, 0, stream>>>(A, Bmat, bias, C, pe, K, lda, ldb, ldc, Nstore, NT, hstride); break;
      case 2: gemm_kernel<2><<<grid, blk, 0, stream>>>(A, Bmat, bias, C, pe, K, lda, ldb, ldc, Nstore, NT, hstride); break;
      default: gemm_kernel<3><<<grid, blk, 0, stream>>>(A, Bmat, bias, C, pe, K, lda, ldb, ldc, Nstore, NT, hstride); break;
    }
  };

  for (int c = 0; c < NC; ++c) {
    const float* x_c = x + (size_t)c * Mc * 83;
    short* h_c = h_bf + (size_t)c * Mc * 288;

    const int xtot = (int)(Mc * 96);
    conv_x_kernel<<<dim3((xtot + 255) / 256), blk, 0, stream>>>(x_c, x_bfc, xtot);

    gemm(2, x_bfc, Wp_b, bp_p, h_c, pe_mod, 96, 96, 96, 288, 288, 3, Mc, 0);

    for (int l = 0; l < 4; ++l) {
      const short* Wqkv_l = Wqkv_b + (size_t)l * 1152 * 288;
      const short* Wo_l   = Wo_b   + (size_t)l * 288 * 384;
      const short* Wf1_l  = Wf1_b  + (size_t)l * 1408 * 288;
      const short* Wf2_l  = Wf2_b  + (size_t)l * 384 * 1408;

      gemm(3, h_c, Wqkv_l, bqkv_p + l * 1152, qkv_bf, nullptr,
           288, 288, 288, 0, 1152, 9, Mc, sec);

      attn_kernel<<<dim3((unsigned)(Mc / 128), 8), blk, 0, stream>>>(
          qkv_bf, qscale, l, Mc);

      gemm_ln_kernel<true><<<dim3((unsigned)(Mc / 128)), dim3(512), 0, stream>>>(
          qkv_bf + 16 * sec, Wo_l, bo_p + l * 384, h_c, n1w + l * 288, n1b + l * 288,
          skip, l, 1, 384, 48, 384, sec);

      ffn_kernel<<<dim3((unsigned)(Mc / 128)), dim3(512), 0, stream>>>(
          h_c, Wf1_l, bf1_p + l * 1408, Wf2_l, bf2_p + l * 384,
          n2w + l * 288, n2b + l * 288);
    }
  }

  head_kernel<<<dim3(1024), blk, 0, stream>>>(h_bf, (float*)d_out,
      bn_w, bn_b, bn_mean, bn_var,
      h1w, h1b, h2w, h2b, h3w, h3b,
      u1w, u1b, u2w, u2b);
}